// Round 18
// baseline (530.892 us; speedup 1.0000x reference)
//
#include <hip/hip_runtime.h>

#define B_ 1024
#define N_ 64
#define T_ 256
#define FB_ 5
#define T2_ 128
#define C_ 128  // 2N

typedef unsigned short u16;
typedef __attribute__((ext_vector_type(8))) short bf16x8;
typedef __attribute__((ext_vector_type(4))) float f32x4;

__device__ __forceinline__ float leaky(float x) { return x >= 0.f ? x : 0.01f * x; }
__device__ __forceinline__ float rcpf(float x) { return __builtin_amdgcn_rcpf(x); }
__device__ __forceinline__ float sigm2(float x) { return rcpf(1.f + __expf(-x)); }
__device__ __forceinline__ float tanh2(float x) { return 1.f - 2.f * rcpf(1.f + __expf(2.f * x)); }
__device__ __forceinline__ unsigned bf16_rne(float f) {
  unsigned u = __float_as_uint(f);
  return (u + 0x7FFFu + ((u >> 16) & 1u)) >> 16;
}
// barrier that does NOT drain vmcnt (keeps global prefetch in flight)
__device__ __forceinline__ void block_sync_lds() {
  __builtin_amdgcn_sched_barrier(0);
  asm volatile("s_waitcnt lgkmcnt(0)" ::: "memory");
  __builtin_amdgcn_s_barrier();
  __builtin_amdgcn_sched_barrier(0);
}

#define MFMA_(A, B, C) __builtin_amdgcn_mfma_f32_16x16x32_bf16(A, B, C, 0, 0, 0)

// ============ fused norm_adj + Xc + bf16 pack, batch-blocked Xf layout ============
// Xf unit per (bt,t): 2048 u16 = [blo(16)][l(4)][grp(4)][e(8)], l = {kh0hi,kh0lo,kh1hi,kh1lo}.
// offsets in u16: blo*128 + l*32 + grp*8 + e. Each 256B batch-slab single-owner.
__device__ __forceinline__ void xc_tile(const float (*HsT)[68], float (*xs)[68], float (*ys)[68],
                                        const float* __restrict__ Xb, int S, int t0, float w,
                                        u16* __restrict__ Xft, int tid) {
  __syncthreads();
  for (int idx = tid; idx < 4096; idx += 256) {
    int j = idx >> 6, tt = idx & 63;
    xs[j][tt] = (t0 + tt < S) ? Xb[j * S + t0 + tt] : 0.f;
  }
  __syncthreads();
  int i0 = (tid & 15) * 4, tl = (tid >> 4) * 4;
  f32x4 a0 = {0, 0, 0, 0}, a1 = {0, 0, 0, 0}, a2 = {0, 0, 0, 0}, a3 = {0, 0, 0, 0};
#pragma unroll 4
  for (int j = 0; j < 64; ++j) {
    f32x4 hv = *(const f32x4*)&HsT[j][i0];
    f32x4 xv = *(const f32x4*)&xs[j][tl];
    a0 += hv * xv[0];
    a1 += hv * xv[1];
    a2 += hv * xv[2];
    a3 += hv * xv[3];
  }
#define YS_T(K, AV)                                     \
  {                                                     \
    f32x4 r;                                            \
    _Pragma("unroll") for (int e = 0; e < 4; ++e)       \
        r[e] = leaky(w * AV[e]);                        \
    *(f32x4*)&ys[tl + K][i0] = r;                       \
  }
  YS_T(0, a0)
  YS_T(1, a1)
  YS_T(2, a2)
  YS_T(3, a3)
#undef YS_T
  __syncthreads();
  // pack: thread (t_l = tid>>2, p = tid&3) converts channels p*16..p*16+15 of row t_l.
  // kh = p>>1, grps (p&1)*2 and (p&1)*2+1. hi slot l = kh*2 at u16 off l*32; lo at +32.
  int t_l = tid >> 2, p = tid & 3;
  if (t0 + t_l < S) {
    const f32x4* yr = (const f32x4*)&ys[t_l][p * 16];
    f32x4 y0 = yr[0], y1 = yr[1], y2 = yr[2], y3 = yr[3];
    bf16x8 hiA, hiB, loA, loB;
#pragma unroll
    for (int e = 0; e < 4; ++e) {
      unsigned h;
      h = bf16_rne(y0[e]); hiA[e] = (short)h;
      loA[e] = (short)bf16_rne(y0[e] - __uint_as_float(h << 16));
      h = bf16_rne(y1[e]); hiA[4 + e] = (short)h;
      loA[4 + e] = (short)bf16_rne(y1[e] - __uint_as_float(h << 16));
      h = bf16_rne(y2[e]); hiB[e] = (short)h;
      loB[e] = (short)bf16_rne(y2[e] - __uint_as_float(h << 16));
      h = bf16_rne(y3[e]); hiB[4 + e] = (short)h;
      loB[4 + e] = (short)bf16_rne(y3[e] - __uint_as_float(h << 16));
    }
    // dst (u16): t*2048 + (p>>1)*64 + (p&1)*16; hiA@+0 hiB@+8 loA@+32 loB@+40
    u16* dst = Xft + (size_t)(t0 + t_l) * 2048 + (p >> 1) * 64 + (p & 1) * 16;
    *(bf16x8*)dst = hiA;
    *(bf16x8*)(dst + 8) = hiB;
    *(bf16x8*)(dst + 32) = loA;
    *(bf16x8*)(dst + 40) = loB;
  }
}

__global__ __launch_bounds__(256) void knorm_xc(
    const float* __restrict__ A, const float* __restrict__ xT, const float* __restrict__ xF,
    const float* __restrict__ wT, const float* __restrict__ wF,
    u16* __restrict__ XfT, u16* __restrict__ XfF) {
  __shared__ float HsT[64][68];  // HsT[j][i]
  __shared__ float dinv[64];
  __shared__ float xs[64][68];
  __shared__ float ys[64][68];
  int b = blockIdx.x, tid = threadIdx.x;
  int bt = b >> 4, blo = b & 15;
  const float* Ab = A + (size_t)b * 4096;
  for (int idx = tid; idx < 4096; idx += 256) {
    int i = idx >> 6, j = idx & 63;
    HsT[j][i] = (i == j) ? 1.f : Ab[idx];
  }
  __syncthreads();
  if (tid < 64) {
    float s = 0.f;
    for (int j = 0; j < 64; ++j) s += HsT[j][tid];
    dinv[tid] = 1.f / sqrtf(s);
  }
  __syncthreads();
  for (int idx = tid; idx < 4096; idx += 256) {
    int j = idx >> 6, i = idx & 63;
    HsT[j][i] *= dinv[i] * dinv[j];
  }
  {
    const float* Xb = xT + (size_t)b * 64 * 256;
    float w = wT[0];
    u16* Xft = XfT + (size_t)bt * 256 * 2048 + blo * 128;
    for (int t0 = 0; t0 < 256; t0 += 64) xc_tile(HsT, xs, ys, Xb, 256, t0, w, Xft, tid);
  }
  {
    const float* Xb = xF + (size_t)b * 64 * 5;
    float w = wF[0];
    u16* Xft = XfF + (size_t)bt * 5 * 2048 + blo * 128;
    xc_tile(HsT, xs, ys, Xb, 5, 0, w, Xft, tid);
  }
}

// ============ MFMA bidirectional GRU (T/F) + embedded kM on the F-blocks' idle CUs ============
__device__ __forceinline__ void axcomp(f32x4 (&AX)[3], const bf16x8 (&XB)[4],
                                       const bf16x8 (&Whi)[3][2], const bf16x8 (&Wlo)[3][2],
                                       const f32x4 (&bI)[3]) {
  AX[0] = bI[0];
  AX[1] = bI[1];
  AX[2] = bI[2];
#pragma unroll
  for (int kh = 0; kh < 2; ++kh) {
    bf16x8 xh = XB[2 * kh], xl = XB[2 * kh + 1];
#pragma unroll
    for (int gi = 0; gi < 3; ++gi) {
      AX[gi] = MFMA_(Whi[gi][kh], xh, AX[gi]);
      AX[gi] = MFMA_(Whi[gi][kh], xl, AX[gi]);
      AX[gi] = MFMA_(Wlo[gi][kh], xh, AX[gi]);
    }
  }
}

__global__ __launch_bounds__(256, 1) void kgru_all(
    const u16* __restrict__ XfT, const u16* __restrict__ XfF,
    const float* __restrict__ Twih_f, const float* __restrict__ Twhh_f,
    const float* __restrict__ Tbih_f, const float* __restrict__ Tbhh_f,
    const float* __restrict__ Twih_b, const float* __restrict__ Twhh_b,
    const float* __restrict__ Tbih_b, const float* __restrict__ Tbhh_b,
    const float* __restrict__ Fwih_f, const float* __restrict__ Fwhh_f,
    const float* __restrict__ Fbih_f, const float* __restrict__ Fbhh_f,
    const float* __restrict__ Fwih_b, const float* __restrict__ Fwhh_b,
    const float* __restrict__ Fbih_b, const float* __restrict__ Fbhh_b,
    u16* __restrict__ gT, u16* __restrict__ gF,
    const float* __restrict__ W1, const float* __restrict__ lTw, const float* __restrict__ lFw,
    const float* __restrict__ lFb, const float* __restrict__ lTb, const float* __restrict__ l1b,
    float* __restrict__ MT, float* __restrict__ MF, float* __restrict__ c0v) {
  __shared__ u16 Hhi[2][16][72];
  __shared__ u16 Hlo[2][16][72];
  __shared__ float W1s[128][129];
  __shared__ float ls[128][32];
  __shared__ float rs[256];
  int tid = threadIdx.x;
  int w = tid >> 6, lane = tid & 63, blo = lane & 15, grp = lane >> 4;
  int bt = blockIdx.x, dir = blockIdx.y, tf = blockIdx.z;
  int S = tf ? 5 : 256;
  const u16* Xf = tf ? XfF : XfT;
  u16* g = tf ? gF : gT;
  const float* wih = tf ? (dir ? Fwih_b : Fwih_f) : (dir ? Twih_b : Twih_f);
  const float* whh = tf ? (dir ? Fwhh_b : Fwhh_f) : (dir ? Twhh_b : Twhh_f);
  const float* bih = tf ? (dir ? Fbih_b : Fbih_f) : (dir ? Tbih_b : Tbih_f);
  const float* bhh = tf ? (dir ? Fbhh_b : Fbhh_f) : (dir ? Tbhh_b : Tbhh_f);

  for (int idx = tid; idx < 16 * 72; idx += 256) {
    ((u16*)Hhi[0])[idx] = 0;
    ((u16*)Hlo[0])[idx] = 0;
  }

  bf16x8 Wih_hi[3][2], Wih_lo[3][2], Whh_hi[3][2], Whh_lo[3][2];
#pragma unroll
  for (int gi = 0; gi < 3; ++gi) {
    int k = (gi * 4 + w) * 16 + blo;
#pragma unroll
    for (int kh = 0; kh < 2; ++kh) {
      int j0 = kh * 32 + grp * 8;
#pragma unroll
      for (int m = 0; m < 2; ++m) {
        const float* src = (m ? whh : wih) + (size_t)k * 64 + j0;
        f32x4 a0 = *(const f32x4*)src;
        f32x4 a1 = *(const f32x4*)(src + 4);
        bf16x8 hi, lo;
#pragma unroll
        for (int e = 0; e < 4; ++e) {
          unsigned h0 = bf16_rne(a0[e]);
          hi[e] = (short)h0;
          lo[e] = (short)bf16_rne(a0[e] - __uint_as_float(h0 << 16));
          unsigned h1 = bf16_rne(a1[e]);
          hi[e + 4] = (short)h1;
          lo[e + 4] = (short)bf16_rne(a1[e] - __uint_as_float(h1 << 16));
        }
        if (m) {
          Whh_hi[gi][kh] = hi;
          Whh_lo[gi][kh] = lo;
        } else {
          Wih_hi[gi][kh] = hi;
          Wih_lo[gi][kh] = lo;
        }
      }
    }
  }
  f32x4 bI[3], bH[3];
#pragma unroll
  for (int gi = 0; gi < 3; ++gi) {
    int k0 = (gi * 4 + w) * 16 + 4 * grp;
    bI[gi] = *(const f32x4*)(bih + k0);
    bH[gi] = *(const f32x4*)(bhh + k0);
  }

  float ho[4] = {0.f, 0.f, 0.f, 0.f};
  int j0q = 16 * w + 4 * grp;
  // batch-blocked Xf: lane (blo,grp) reads 4x 16B at l*32 u16 within its 128-u16 slab
  const u16* xbase = Xf + (size_t)bt * S * 2048 + blo * 128 + grp * 8;
  long long sstep = dir ? -4096LL : 4096LL;
  long long gstep = dir ? -256LL : 256LL;

  bf16x8 x0[4], x1[4], x2[4], x3[4];
#define LOADX(DST, TR)                            \
  {                                               \
    const u16* xp = xbase + (size_t)(TR) * 2048;  \
    DST[0] = *(const bf16x8*)(xp);                \
    DST[1] = *(const bf16x8*)(xp + 32);           \
    DST[2] = *(const bf16x8*)(xp + 64);           \
    DST[3] = *(const bf16x8*)(xp + 96);           \
  }
  LOADX(x0, dir ? (S - 1) : 0)
  if (S > 1) LOADX(x1, dir ? (S - 2) : 1)
  if (S > 2) LOADX(x2, dir ? (S - 3) : 2)
  const u16* xw = xbase + (size_t)(dir ? (S >= 4 ? S - 4 : 0) : 3) * 2048;
  u16* gp = g + ((size_t)(bt * 16 + blo) * S + (dir ? S - 1 : 0)) * 128 + dir * 64 + j0q;

  f32x4 axA[3], axB[3];
  axcomp(axA, x0, Wih_hi, Wih_lo, bI);
  block_sync_lds();

#define GSTEP(KK, XAX, XLD, AXC, AXN, PR, PW)                                        \
  {                                                                                  \
    int t = tbase + KK;                                                              \
    if (t < S) {                                                                     \
      bf16x8 h0h = *(const bf16x8*)&Hhi[PR][blo][grp * 8];                           \
      bf16x8 h0l = *(const bf16x8*)&Hlo[PR][blo][grp * 8];                           \
      bf16x8 h1h = *(const bf16x8*)&Hhi[PR][blo][32 + grp * 8];                      \
      bf16x8 h1l = *(const bf16x8*)&Hlo[PR][blo][32 + grp * 8];                      \
      if (t + 3 < S) {                                                               \
        XLD[0] = *(const bf16x8*)(xw);                                               \
        XLD[1] = *(const bf16x8*)(xw + 32);                                          \
        XLD[2] = *(const bf16x8*)(xw + 64);                                          \
        XLD[3] = *(const bf16x8*)(xw + 96);                                          \
        xw = (const u16*)((const char*)xw + sstep);                                  \
      }                                                                              \
      if (t + 1 < S) axcomp(AXN, XAX, Wih_hi, Wih_lo, bI);                           \
      f32x4 ahr = bH[0], ahz = bH[1], ahn = bH[2];                                   \
      ahr = MFMA_(Whh_hi[0][0], h0h, ahr);                                           \
      ahr = MFMA_(Whh_hi[0][0], h0l, ahr);                                           \
      ahr = MFMA_(Whh_lo[0][0], h0h, ahr);                                           \
      ahz = MFMA_(Whh_hi[1][0], h0h, ahz);                                           \
      ahz = MFMA_(Whh_hi[1][0], h0l, ahz);                                           \
      ahz = MFMA_(Whh_lo[1][0], h0h, ahz);                                           \
      ahn = MFMA_(Whh_hi[2][0], h0h, ahn);                                           \
      ahn = MFMA_(Whh_hi[2][0], h0l, ahn);                                           \
      ahn = MFMA_(Whh_lo[2][0], h0h, ahn);                                           \
      ahr = MFMA_(Whh_hi[0][1], h1h, ahr);                                           \
      ahr = MFMA_(Whh_hi[0][1], h1l, ahr);                                           \
      ahr = MFMA_(Whh_lo[0][1], h1h, ahr);                                           \
      ahz = MFMA_(Whh_hi[1][1], h1h, ahz);                                           \
      ahz = MFMA_(Whh_hi[1][1], h1l, ahz);                                           \
      ahz = MFMA_(Whh_lo[1][1], h1h, ahz);                                           \
      ahn = MFMA_(Whh_hi[2][1], h1h, ahn);                                           \
      ahn = MFMA_(Whh_hi[2][1], h1l, ahn);                                           \
      ahn = MFMA_(Whh_lo[2][1], h1h, ahn);                                           \
      u16 hi_u[4], lo_u[4];                                                          \
      _Pragma("unroll") for (int u = 0; u < 4; ++u) {                                \
        float r = sigm2(AXC[0][u] + ahr[u]);                                         \
        float z = sigm2(AXC[1][u] + ahz[u]);                                         \
        float n = tanh2(AXC[2][u] + r * ahn[u]);                                     \
        float h = n + z * (ho[u] - n);                                               \
        ho[u] = h;                                                                   \
        unsigned hb = (__float_as_uint(h) + 0x8000u) >> 16;                          \
        hi_u[u] = (u16)hb;                                                           \
        float rr = h - __uint_as_float(hb << 16);                                    \
        lo_u[u] = (u16)((__float_as_uint(rr) + 0x8000u) >> 16);                      \
      }                                                                              \
      ushort4 h4;                                                                    \
      h4.x = hi_u[0]; h4.y = hi_u[1]; h4.z = hi_u[2]; h4.w = hi_u[3];                \
      ushort4 l4;                                                                    \
      l4.x = lo_u[0]; l4.y = lo_u[1]; l4.z = lo_u[2]; l4.w = lo_u[3];                \
      *(ushort4*)&Hhi[PW][blo][j0q] = h4;                                            \
      *(ushort4*)&Hlo[PW][blo][j0q] = l4;                                            \
      *(ushort4*)gp = h4;                                                            \
      gp = (u16*)((char*)gp + gstep);                                                \
      block_sync_lds();                                                              \
    }                                                                                \
  }

  for (int tbase = 0; tbase < S; tbase += 4) {
    GSTEP(0, x1, x3, axA, axB, 0, 1)
    GSTEP(1, x2, x0, axB, axA, 1, 0)
    GSTEP(2, x3, x1, axA, axB, 0, 1)
    GSTEP(3, x0, x2, axB, axA, 1, 0)
  }
#undef GSTEP
#undef LOADX

  // ---- embedded kM: F-blocks (tf==1) run the MT/MF/c0 jobs on otherwise-idle CUs ----
  if (tf == 1) {
    int jid = bt * 2 + dir;  // 0..127
    for (int job = jid; job < 576; job += 128) {
      __syncthreads();
      int o = job & 63, by = job >> 6;
      if (by < 8) {
        int t0 = by * 32;
        const float* Wo = W1 + (size_t)o * 32768 + 16384;
        for (int idx = tid; idx < 16384; idx += 256) W1s[idx >> 7][idx & 127] = Wo[idx];
        for (int idx = tid; idx < 4096; idx += 256)
          ls[idx >> 5][idx & 31] = lTw[(idx >> 5) * 256 + t0 + (idx & 31)];
        __syncthreads();
        int c = tid & 127, th = tid >> 7;
        float acc[16];
#pragma unroll
        for (int q = 0; q < 16; ++q) acc[q] = 0.f;
        for (int t2 = 0; t2 < 128; ++t2) {
          float wv = W1s[c][t2];
#pragma unroll
          for (int q = 0; q < 16; ++q) acc[q] += wv * ls[t2][th + 2 * q];
        }
        float* Mo = MT + (size_t)o * 32768;
#pragma unroll
        for (int q = 0; q < 16; ++q) Mo[(t0 + th + 2 * q) * 128 + c] = acc[q];
      } else {
        const float* Wo = W1 + (size_t)o * 32768;
        for (int idx = tid; idx < 16384; idx += 256) W1s[idx >> 7][idx & 127] = Wo[idx];
        for (int idx = tid; idx < 640; idx += 256) ls[idx / 5][idx % 5] = lFw[idx];
        __syncthreads();
        int c = tid & 127, fh = tid >> 7;
        float acc[3] = {0.f, 0.f, 0.f};
        for (int t2 = 0; t2 < 128; ++t2) {
          float wv = W1s[c][t2];
#pragma unroll
          for (int q = 0; q < 3; ++q) {
            int f = fh + 2 * q;
            if (f < 5) acc[q] += wv * ls[t2][f];
          }
        }
#pragma unroll
        for (int q = 0; q < 3; ++q) {
          int f = fh + 2 * q;
          if (f < 5) MF[(size_t)o * 640 + f * 128 + c] = acc[q];
        }
        float s = 0.f;
        for (int idx = tid; idx < 16384; idx += 256) {
          int t2 = idx & 127;
          s += Wo[idx] * lFb[t2] + Wo[16384 + idx] * lTb[t2];
        }
        rs[tid] = s;
        __syncthreads();
        for (int off = 128; off; off >>= 1) {
          if (tid < off) rs[tid] += rs[tid + off];
          __syncthreads();
        }
        if (tid == 0) c0v[o] = l1b[o] + rs[0];
      }
    }
  }
}

// ============ BN stats (T and F in one grid) ============
__global__ __launch_bounds__(256) void kbn_all(
    const u16* __restrict__ gTp, const u16* __restrict__ gFp,
    const float* __restrict__ gamT, const float* __restrict__ betT,
    const float* __restrict__ gamF, const float* __restrict__ betF,
    float* __restrict__ sdT, float* __restrict__ sdF) {
  int bid = blockIdx.x, tid = threadIdx.x;
  const u16* g;
  const float *gam, *bet;
  float* sd;
  int S, t;
  if (bid < 256) {
    g = gTp; S = 256; t = bid; gam = gamT; bet = betT; sd = sdT;
  } else {
    g = gFp; S = 5; t = bid - 256; gam = gamF; bet = betF; sd = sdF;
  }
  float s = 0.f, s2 = 0.f;
  for (int unit = tid; unit < 32768; unit += 256) {
    int b = unit >> 5, c4 = (unit & 31) * 4;
    ushort4 u = *(const ushort4*)(g + ((size_t)b * S + t) * 128 + c4);
    float v0 = __uint_as_float((unsigned)u.x << 16);
    float v1 = __uint_as_float((unsigned)u.y << 16);
    float v2 = __uint_as_float((unsigned)u.z << 16);
    float v3 = __uint_as_float((unsigned)u.w << 16);
    s += v0 + v1 + v2 + v3;
    s2 += v0 * v0 + v1 * v1 + v2 * v2 + v3 * v3;
  }
  __shared__ float rs[256], rq[256];
  rs[tid] = s;
  rq[tid] = s2;
  __syncthreads();
  for (int off = 128; off; off >>= 1) {
    if (tid < off) {
      rs[tid] += rs[tid + off];
      rq[tid] += rq[tid + off];
    }
    __syncthreads();
  }
  if (tid == 0) {
    float inv_n = 1.f / (float)(B_ * C_);
    float m = rs[0] * inv_n;
    float var = rq[0] * inv_n - m * m;
    float inv = 1.f / sqrtf(var + 1e-5f);
    float sc = gam[t] * inv;
    sd[2 * t] = sc;
    sd[2 * t + 1] = bet[t] - m * sc;
  }
}

// ============ kchunk (32-batch/nt=16/17-slot form) ============
__global__ __launch_bounds__(256) void kchunk_all(
    const u16* __restrict__ gTp, const u16* __restrict__ gFp,
    const float* __restrict__ sdT, const float* __restrict__ sdF,
    const float* __restrict__ MT, const float* __restrict__ MF,
    float* __restrict__ part) {
  __shared__ float gs[32][132];
  __shared__ float Ms[64][132];
  int tid = threadIdx.x;
  int b0 = blockIdx.x * 32;
  int by = blockIdx.y;
  const u16* g;
  const float *sd, *M;
  int S, nt, t0, slot;
  if (by < 16) {
    g = gTp; sd = sdT; M = MT; S = 256; nt = 16; t0 = by * 16; slot = by;
  } else {
    g = gFp; sd = sdF; M = MF; S = 5; nt = 5; t0 = 0; slot = 16;
  }
  int ot = tid & 31, bt = tid >> 5;
  float acc[4][2];
#pragma unroll
  for (int i = 0; i < 4; ++i) {
    acc[i][0] = 0.f;
    acc[i][1] = 0.f;
  }
  for (int t = t0; t < t0 + nt; ++t) {
    __syncthreads();
    float sc = sd[2 * t], dd = sd[2 * t + 1];
    for (int idx = tid; idx < 1024; idx += 256) {
      int bb = idx >> 5, c4 = (idx & 31) * 4;
      ushort4 u = *(const ushort4*)(g + ((size_t)(b0 + bb) * S + t) * 128 + c4);
      gs[bb][c4 + 0] = __uint_as_float((unsigned)u.x << 16) * sc + dd;
      gs[bb][c4 + 1] = __uint_as_float((unsigned)u.y << 16) * sc + dd;
      gs[bb][c4 + 2] = __uint_as_float((unsigned)u.z << 16) * sc + dd;
      gs[bb][c4 + 3] = __uint_as_float((unsigned)u.w << 16) * sc + dd;
    }
    for (int idx = tid; idx < 2048; idx += 256) {
      int o = idx >> 5, c4 = (idx & 31) * 4;
      *(float4*)&Ms[o][c4] = *(const float4*)(M + ((size_t)o * S + t) * 128 + c4);
    }
    __syncthreads();
    for (int c = 0; c < 128; c += 4) {
      f32x4 m0 = *(const f32x4*)&Ms[ot][c];
      f32x4 m1 = *(const f32x4*)&Ms[ot + 32][c];
#pragma unroll
      for (int i = 0; i < 4; ++i) {
        f32x4 gv = *(const f32x4*)&gs[bt * 4 + i][c];
        acc[i][0] += gv[0] * m0[0] + gv[1] * m0[1] + gv[2] * m0[2] + gv[3] * m0[3];
        acc[i][1] += gv[0] * m1[0] + gv[1] * m1[1] + gv[2] * m1[2] + gv[3] * m1[3];
      }
    }
  }
#pragma unroll
  for (int i = 0; i < 4; ++i) {
    part[((size_t)slot * 1024 + b0 + bt * 4 + i) * 64 + ot] = acc[i][0];
    part[((size_t)slot * 1024 + b0 + bt * 4 + i) * 64 + ot + 32] = acc[i][1];
  }
}

// ============ finalize ============
__global__ __launch_bounds__(64) void kfin(const float* __restrict__ part,
                                           const float* __restrict__ c0,
                                           const float* __restrict__ l2w,
                                           const float* __restrict__ l2b,
                                           float* __restrict__ outp) {
  int b = blockIdx.x, o = threadIdx.x;
  float y = c0[o];
  for (int s = 0; s < 17; ++s) y += part[((size_t)s * 1024 + b) * 64 + o];
  y = leaky(y);
  __shared__ float a[64];
  a[o] = y;
  __syncthreads();
  if (o < 3) {
    float r = l2b[o];
    for (int j = 0; j < 64; ++j) r += l2w[o * 64 + j] * a[j];
    outp[b * 3 + o] = r;
  }
}

extern "C" void kernel_launch(void* const* d_in, const int* in_sizes, int n_in,
                              void* d_out, int out_size, void* d_ws, size_t ws_size,
                              hipStream_t stream) {
  const float* x_T = (const float*)d_in[0];
  const float* x_F = (const float*)d_in[1];
  const float* A = (const float*)d_in[2];
  const float* gcnw_F = (const float*)d_in[3];
  const float* gFwih_f = (const float*)d_in[4];
  const float* gFwhh_f = (const float*)d_in[5];
  const float* gFbih_f = (const float*)d_in[6];
  const float* gFbhh_f = (const float*)d_in[7];
  const float* gFwih_b = (const float*)d_in[8];
  const float* gFwhh_b = (const float*)d_in[9];
  const float* gFbih_b = (const float*)d_in[10];
  const float* gFbhh_b = (const float*)d_in[11];
  const float* bnFg = (const float*)d_in[12];
  const float* bnFb = (const float*)d_in[13];
  const float* gcnw_T = (const float*)d_in[14];
  const float* gTwih_f = (const float*)d_in[15];
  const float* gTwhh_f = (const float*)d_in[16];
  const float* gTbih_f = (const float*)d_in[17];
  const float* gTbhh_f = (const float*)d_in[18];
  const float* gTwih_b = (const float*)d_in[19];
  const float* gTwhh_b = (const float*)d_in[20];
  const float* gTbih_b = (const float*)d_in[21];
  const float* gTbhh_b = (const float*)d_in[22];
  const float* bnTg = (const float*)d_in[23];
  const float* bnTb = (const float*)d_in[24];
  const float* linF_w = (const float*)d_in[25];
  const float* linF_b = (const float*)d_in[26];
  const float* linT_w = (const float*)d_in[27];
  const float* linT_b = (const float*)d_in[28];
  const float* lin1_w = (const float*)d_in[29];
  const float* lin1_b = (const float*)d_in[30];
  const float* lin2_w = (const float*)d_in[31];
  const float* lin2_b = (const float*)d_in[32];

  char* w8 = (char*)d_ws;
  size_t off = 0;
  auto take = [&](size_t bytes) {
    void* p = w8 + off;
    off += (bytes + 255) & ~(size_t)255;
    return p;
  };
  u16* XfT = (u16*)take((size_t)64 * 256 * 2048 * 2);
  u16* XfF = (u16*)take((size_t)64 * 5 * 2048 * 2);
  u16* gT = (u16*)take((size_t)1024 * 256 * 128 * 2);
  u16* gF = (u16*)take((size_t)1024 * 5 * 128 * 2);
  float* sdT = (float*)take(512 * 4);
  float* sdF = (float*)take(16 * 4);
  float* MT = (float*)take((size_t)64 * 256 * 128 * 4);
  float* MF = (float*)take((size_t)64 * 5 * 128 * 4);
  float* c0 = (float*)take(64 * 4);
  float* part = (float*)take((size_t)17 * 1024 * 64 * 4);

  knorm_xc<<<1024, 256, 0, stream>>>(A, x_T, x_F, gcnw_T, gcnw_F, XfT, XfF);
  kgru_all<<<dim3(64, 2, 2), 256, 0, stream>>>(
      XfT, XfF, gTwih_f, gTwhh_f, gTbih_f, gTbhh_f, gTwih_b, gTwhh_b, gTbih_b, gTbhh_b,
      gFwih_f, gFwhh_f, gFbih_f, gFbhh_f, gFwih_b, gFwhh_b, gFbih_b, gFbhh_b, gT, gF,
      lin1_w, linT_w, linF_w, linF_b, linT_b, lin1_b, MT, MF, c0);
  kbn_all<<<261, 256, 0, stream>>>(gT, gF, bnTg, bnTb, bnFg, bnFb, sdT, sdF);
  kchunk_all<<<dim3(32, 17), 256, 0, stream>>>(gT, gF, sdT, sdF, MT, MF, part);
  kfin<<<1024, 64, 0, stream>>>(part, c0, lin2_w, lin2_b, (float*)d_out);
}

// Round 19
// 484.440 us; speedup vs baseline: 1.0959x; 1.0959x over previous
//
#include <hip/hip_runtime.h>

#define B_ 1024
#define N_ 64
#define T_ 256
#define FB_ 5
#define T2_ 128
#define C_ 128  // 2N

typedef unsigned short u16;
typedef __attribute__((ext_vector_type(8))) short bf16x8;
typedef __attribute__((ext_vector_type(4))) float f32x4;

__device__ __forceinline__ float leaky(float x) { return x >= 0.f ? x : 0.01f * x; }
__device__ __forceinline__ float rcpf(float x) { return __builtin_amdgcn_rcpf(x); }
__device__ __forceinline__ float sigm2(float x) { return rcpf(1.f + __expf(-x)); }
__device__ __forceinline__ float tanh2(float x) { return 1.f - 2.f * rcpf(1.f + __expf(2.f * x)); }
__device__ __forceinline__ unsigned bf16_rne(float f) {
  unsigned u = __float_as_uint(f);
  return (u + 0x7FFFu + ((u >> 16) & 1u)) >> 16;
}
// barrier that does NOT drain vmcnt (keeps global prefetch in flight)
__device__ __forceinline__ void block_sync_lds() {
  __builtin_amdgcn_sched_barrier(0);
  asm volatile("s_waitcnt lgkmcnt(0)" ::: "memory");
  __builtin_amdgcn_s_barrier();
  __builtin_amdgcn_sched_barrier(0);
}

#define MFMA_(A, B, C) __builtin_amdgcn_mfma_f32_16x16x32_bf16(A, B, C, 0, 0, 0)

// ============ fused norm_adj + Xc(T) + Xc(F): HsT in LDS; 2 LDS instr / 16 FMA ============
__device__ __forceinline__ void xc_tile(const float (*HsT)[68], float (*xs)[68],
                                        const float* __restrict__ Xb, int S, int t0, float w,
                                        float* __restrict__ Ob, int tid) {
  __syncthreads();
  for (int idx = tid; idx < 4096; idx += 256) {
    int j = idx >> 6, tt = idx & 63;
    xs[j][tt] = (t0 + tt < S) ? Xb[j * S + t0 + tt] : 0.f;
  }
  __syncthreads();
  int i0 = (tid & 15) * 4, tl = (tid >> 4) * 4;
  f32x4 a0 = {0, 0, 0, 0}, a1 = {0, 0, 0, 0}, a2 = {0, 0, 0, 0}, a3 = {0, 0, 0, 0};
#pragma unroll 4
  for (int j = 0; j < 64; ++j) {
    f32x4 hv = *(const f32x4*)&HsT[j][i0];
    f32x4 xv = *(const f32x4*)&xs[j][tl];
    a0 += hv * xv[0];
    a1 += hv * xv[1];
    a2 += hv * xv[2];
    a3 += hv * xv[3];
  }
#define STORE_T(K, AV)                                  \
  {                                                     \
    int t = t0 + tl + K;                                \
    if (t < S) {                                        \
      f32x4 r;                                          \
      _Pragma("unroll") for (int e = 0; e < 4; ++e)     \
          r[e] = leaky(w * AV[e]);                      \
      *(f32x4*)&Ob[(size_t)t * 64 + i0] = r;            \
    }                                                   \
  }
  STORE_T(0, a0)
  STORE_T(1, a1)
  STORE_T(2, a2)
  STORE_T(3, a3)
#undef STORE_T
}

__global__ __launch_bounds__(256) void knorm_xc(
    const float* __restrict__ A, const float* __restrict__ xT, const float* __restrict__ xF,
    const float* __restrict__ wT, const float* __restrict__ wF,
    float* __restrict__ XpT, float* __restrict__ XpF) {
  __shared__ float HsT[64][68];  // HsT[j][i]
  __shared__ float dinv[64];
  __shared__ float xs[64][68];
  int b = blockIdx.x, tid = threadIdx.x;
  const float* Ab = A + (size_t)b * 4096;
  for (int idx = tid; idx < 4096; idx += 256) {
    int i = idx >> 6, j = idx & 63;
    HsT[j][i] = (i == j) ? 1.f : Ab[idx];
  }
  __syncthreads();
  if (tid < 64) {
    float s = 0.f;
    for (int j = 0; j < 64; ++j) s += HsT[j][tid];
    dinv[tid] = 1.f / sqrtf(s);
  }
  __syncthreads();
  for (int idx = tid; idx < 4096; idx += 256) {
    int j = idx >> 6, i = idx & 63;
    HsT[j][i] *= dinv[i] * dinv[j];
  }
  {
    const float* Xb = xT + (size_t)b * 64 * 256;
    float w = wT[0];
    float* Ob = XpT + (size_t)b * 256 * 64;
    for (int t0 = 0; t0 < 256; t0 += 64) xc_tile(HsT, xs, Xb, 256, t0, w, Ob, tid);
  }
  {
    const float* Xb = xF + (size_t)b * 64 * 5;
    float w = wF[0];
    float* Ob = XpF + (size_t)b * 5 * 64;
    xc_tile(HsT, xs, Xb, 5, 0, w, Ob, tid);
  }
}

// ============ repack Xp -> bf16 hi/lo lane-major MFMA B-fragments ============
__global__ __launch_bounds__(256) void kxq_all(const float* __restrict__ XpT,
                                               const float* __restrict__ XpF,
                                               u16* __restrict__ XfT, u16* __restrict__ XfF) {
  __shared__ float xs[4][16][68];
  int bt = blockIdx.x, by = blockIdx.y, tid = threadIdx.x;
  const float* Xp;
  u16* Xf;
  int S, t0;
  if (by < 64) {
    Xp = XpT; Xf = XfT; S = 256; t0 = by * 4;
  } else {
    Xp = XpF; Xf = XfF; S = 5; t0 = (by - 64) * 4;
  }
  for (int idx = tid; idx < 1024; idx += 256) {
    int b_l = idx >> 6, rest = idx & 63, t_l = rest >> 4, c = rest & 15;
    float4 v = {0.f, 0.f, 0.f, 0.f};
    if (t0 + t_l < S)
      v = *(const float4*)(Xp + ((size_t)(bt * 16 + b_l) * S + t0 + t_l) * 64 + c * 4);
    *(float4*)&xs[t_l][b_l][c * 4] = v;
  }
  __syncthreads();
  int t_l = tid >> 6, lane = tid & 63, blo = lane & 15, grp = lane >> 4;
  int t = t0 + t_l;
  if (t >= S) return;
#pragma unroll
  for (int kh = 0; kh < 2; ++kh) {
    const f32x4* src = (const f32x4*)&xs[t_l][blo][kh * 32 + grp * 8];
    f32x4 a0 = src[0], a1 = src[1];
    bf16x8 hi, lo;
#pragma unroll
    for (int e = 0; e < 4; ++e) {
      unsigned h0 = bf16_rne(a0[e]);
      hi[e] = (short)h0;
      lo[e] = (short)bf16_rne(a0[e] - __uint_as_float(h0 << 16));
      unsigned h1 = bf16_rne(a1[e]);
      hi[e + 4] = (short)h1;
      lo[e + 4] = (short)bf16_rne(a1[e] - __uint_as_float(h1 << 16));
    }
    u16* dst = Xf + (size_t)(bt * S + t) * 2048 + (size_t)kh * 1024 + lane * 8;
    *(bf16x8*)dst = hi;
    *(bf16x8*)(dst + 512) = lo;
  }
}

// ============ MFMA bidirectional GRU (T/F) + embedded kM on the F-blocks' idle CUs ============
__device__ __forceinline__ void axcomp(f32x4 (&AX)[3], const bf16x8 (&XB)[4],
                                       const bf16x8 (&Whi)[3][2], const bf16x8 (&Wlo)[3][2],
                                       const f32x4 (&bI)[3]) {
  AX[0] = bI[0];
  AX[1] = bI[1];
  AX[2] = bI[2];
#pragma unroll
  for (int kh = 0; kh < 2; ++kh) {
    bf16x8 xh = XB[2 * kh], xl = XB[2 * kh + 1];
#pragma unroll
    for (int gi = 0; gi < 3; ++gi) {
      AX[gi] = MFMA_(Whi[gi][kh], xh, AX[gi]);
      AX[gi] = MFMA_(Whi[gi][kh], xl, AX[gi]);
      AX[gi] = MFMA_(Wlo[gi][kh], xh, AX[gi]);
    }
  }
}

__global__ __launch_bounds__(256, 1) void kgru_all(
    const u16* __restrict__ XfT, const u16* __restrict__ XfF,
    const float* __restrict__ Twih_f, const float* __restrict__ Twhh_f,
    const float* __restrict__ Tbih_f, const float* __restrict__ Tbhh_f,
    const float* __restrict__ Twih_b, const float* __restrict__ Twhh_b,
    const float* __restrict__ Tbih_b, const float* __restrict__ Tbhh_b,
    const float* __restrict__ Fwih_f, const float* __restrict__ Fwhh_f,
    const float* __restrict__ Fbih_f, const float* __restrict__ Fbhh_f,
    const float* __restrict__ Fwih_b, const float* __restrict__ Fwhh_b,
    const float* __restrict__ Fbih_b, const float* __restrict__ Fbhh_b,
    u16* __restrict__ gT, u16* __restrict__ gF,
    const float* __restrict__ W1, const float* __restrict__ lTw, const float* __restrict__ lFw,
    const float* __restrict__ lFb, const float* __restrict__ lTb, const float* __restrict__ l1b,
    float* __restrict__ MT, float* __restrict__ MF, float* __restrict__ c0v) {
  __shared__ u16 Hhi[2][16][72];
  __shared__ u16 Hlo[2][16][72];
  __shared__ float W1s[128][129];
  __shared__ float ls[128][32];
  __shared__ float rs[256];
  int tid = threadIdx.x;
  int w = tid >> 6, lane = tid & 63, blo = lane & 15, grp = lane >> 4;
  int bt = blockIdx.x, dir = blockIdx.y, tf = blockIdx.z;
  int S = tf ? 5 : 256;
  const u16* Xf = tf ? XfF : XfT;
  u16* g = tf ? gF : gT;
  const float* wih = tf ? (dir ? Fwih_b : Fwih_f) : (dir ? Twih_b : Twih_f);
  const float* whh = tf ? (dir ? Fwhh_b : Fwhh_f) : (dir ? Twhh_b : Twhh_f);
  const float* bih = tf ? (dir ? Fbih_b : Fbih_f) : (dir ? Tbih_b : Tbih_f);
  const float* bhh = tf ? (dir ? Fbhh_b : Fbhh_f) : (dir ? Tbhh_b : Tbhh_f);

  for (int idx = tid; idx < 16 * 72; idx += 256) {
    ((u16*)Hhi[0])[idx] = 0;
    ((u16*)Hlo[0])[idx] = 0;
  }

  bf16x8 Wih_hi[3][2], Wih_lo[3][2], Whh_hi[3][2], Whh_lo[3][2];
#pragma unroll
  for (int gi = 0; gi < 3; ++gi) {
    int k = (gi * 4 + w) * 16 + blo;
#pragma unroll
    for (int kh = 0; kh < 2; ++kh) {
      int j0 = kh * 32 + grp * 8;
#pragma unroll
      for (int m = 0; m < 2; ++m) {
        const float* src = (m ? whh : wih) + (size_t)k * 64 + j0;
        f32x4 a0 = *(const f32x4*)src;
        f32x4 a1 = *(const f32x4*)(src + 4);
        bf16x8 hi, lo;
#pragma unroll
        for (int e = 0; e < 4; ++e) {
          unsigned h0 = bf16_rne(a0[e]);
          hi[e] = (short)h0;
          lo[e] = (short)bf16_rne(a0[e] - __uint_as_float(h0 << 16));
          unsigned h1 = bf16_rne(a1[e]);
          hi[e + 4] = (short)h1;
          lo[e + 4] = (short)bf16_rne(a1[e] - __uint_as_float(h1 << 16));
        }
        if (m) {
          Whh_hi[gi][kh] = hi;
          Whh_lo[gi][kh] = lo;
        } else {
          Wih_hi[gi][kh] = hi;
          Wih_lo[gi][kh] = lo;
        }
      }
    }
  }
  f32x4 bI[3], bH[3];
#pragma unroll
  for (int gi = 0; gi < 3; ++gi) {
    int k0 = (gi * 4 + w) * 16 + 4 * grp;
    bI[gi] = *(const f32x4*)(bih + k0);
    bH[gi] = *(const f32x4*)(bhh + k0);
  }

  float ho[4] = {0.f, 0.f, 0.f, 0.f};
  int j0q = 16 * w + 4 * grp;
  const u16* xbase = Xf + (size_t)bt * S * 2048 + lane * 8;
  long long sstep = dir ? -4096LL : 4096LL;
  long long gstep = dir ? -256LL : 256LL;

  bf16x8 x0[4], x1[4], x2[4], x3[4];
#define LOADX(DST, TR)                            \
  {                                               \
    const u16* xp = xbase + (size_t)(TR) * 2048;  \
    DST[0] = *(const bf16x8*)(xp);                \
    DST[1] = *(const bf16x8*)(xp + 512);          \
    DST[2] = *(const bf16x8*)(xp + 1024);         \
    DST[3] = *(const bf16x8*)(xp + 1536);         \
  }
  LOADX(x0, dir ? (S - 1) : 0)
  if (S > 1) LOADX(x1, dir ? (S - 2) : 1)
  if (S > 2) LOADX(x2, dir ? (S - 3) : 2)
  const u16* xw = xbase + (size_t)(dir ? (S >= 4 ? S - 4 : 0) : 3) * 2048;
  u16* gp = g + ((size_t)(bt * 16 + blo) * S + (dir ? S - 1 : 0)) * 128 + dir * 64 + j0q;

  f32x4 axA[3], axB[3];
  axcomp(axA, x0, Wih_hi, Wih_lo, bI);
  block_sync_lds();

#define GSTEP(KK, XAX, XLD, AXC, AXN, PR, PW)                                        \
  {                                                                                  \
    int t = tbase + KK;                                                              \
    if (t < S) {                                                                     \
      bf16x8 h0h = *(const bf16x8*)&Hhi[PR][blo][grp * 8];                           \
      bf16x8 h0l = *(const bf16x8*)&Hlo[PR][blo][grp * 8];                           \
      bf16x8 h1h = *(const bf16x8*)&Hhi[PR][blo][32 + grp * 8];                      \
      bf16x8 h1l = *(const bf16x8*)&Hlo[PR][blo][32 + grp * 8];                      \
      if (t + 3 < S) {                                                               \
        XLD[0] = *(const bf16x8*)(xw);                                               \
        XLD[1] = *(const bf16x8*)(xw + 512);                                         \
        XLD[2] = *(const bf16x8*)(xw + 1024);                                        \
        XLD[3] = *(const bf16x8*)(xw + 1536);                                        \
        xw = (const u16*)((const char*)xw + sstep);                                  \
      }                                                                              \
      if (t + 1 < S) axcomp(AXN, XAX, Wih_hi, Wih_lo, bI);                           \
      f32x4 ahr = bH[0], ahz = bH[1], ahn = bH[2];                                   \
      ahr = MFMA_(Whh_hi[0][0], h0h, ahr);                                           \
      ahr = MFMA_(Whh_hi[0][0], h0l, ahr);                                           \
      ahr = MFMA_(Whh_lo[0][0], h0h, ahr);                                           \
      ahz = MFMA_(Whh_hi[1][0], h0h, ahz);                                           \
      ahz = MFMA_(Whh_hi[1][0], h0l, ahz);                                           \
      ahz = MFMA_(Whh_lo[1][0], h0h, ahz);                                           \
      ahn = MFMA_(Whh_hi[2][0], h0h, ahn);                                           \
      ahn = MFMA_(Whh_hi[2][0], h0l, ahn);                                           \
      ahn = MFMA_(Whh_lo[2][0], h0h, ahn);                                           \
      ahr = MFMA_(Whh_hi[0][1], h1h, ahr);                                           \
      ahr = MFMA_(Whh_hi[0][1], h1l, ahr);                                           \
      ahr = MFMA_(Whh_lo[0][1], h1h, ahr);                                           \
      ahz = MFMA_(Whh_hi[1][1], h1h, ahz);                                           \
      ahz = MFMA_(Whh_hi[1][1], h1l, ahz);                                           \
      ahz = MFMA_(Whh_lo[1][1], h1h, ahz);                                           \
      ahn = MFMA_(Whh_hi[2][1], h1h, ahn);                                           \
      ahn = MFMA_(Whh_hi[2][1], h1l, ahn);                                           \
      ahn = MFMA_(Whh_lo[2][1], h1h, ahn);                                           \
      u16 hi_u[4], lo_u[4];                                                          \
      _Pragma("unroll") for (int u = 0; u < 4; ++u) {                                \
        float r = sigm2(AXC[0][u] + ahr[u]);                                         \
        float z = sigm2(AXC[1][u] + ahz[u]);                                         \
        float n = tanh2(AXC[2][u] + r * ahn[u]);                                     \
        float h = n + z * (ho[u] - n);                                               \
        ho[u] = h;                                                                   \
        unsigned hb = (__float_as_uint(h) + 0x8000u) >> 16;                          \
        hi_u[u] = (u16)hb;                                                           \
        float rr = h - __uint_as_float(hb << 16);                                    \
        lo_u[u] = (u16)((__float_as_uint(rr) + 0x8000u) >> 16);                      \
      }                                                                              \
      ushort4 h4;                                                                    \
      h4.x = hi_u[0]; h4.y = hi_u[1]; h4.z = hi_u[2]; h4.w = hi_u[3];                \
      ushort4 l4;                                                                    \
      l4.x = lo_u[0]; l4.y = lo_u[1]; l4.z = lo_u[2]; l4.w = lo_u[3];                \
      *(ushort4*)&Hhi[PW][blo][j0q] = h4;                                            \
      *(ushort4*)&Hlo[PW][blo][j0q] = l4;                                            \
      *(ushort4*)gp = h4;                                                            \
      gp = (u16*)((char*)gp + gstep);                                                \
      block_sync_lds();                                                              \
    }                                                                                \
  }

  for (int tbase = 0; tbase < S; tbase += 4) {
    GSTEP(0, x1, x3, axA, axB, 0, 1)
    GSTEP(1, x2, x0, axB, axA, 1, 0)
    GSTEP(2, x3, x1, axA, axB, 0, 1)
    GSTEP(3, x0, x2, axB, axA, 1, 0)
  }
#undef GSTEP
#undef LOADX

  // ---- embedded kM: F-blocks (tf==1) run the MT/MF/c0 jobs on otherwise-idle CUs ----
  if (tf == 1) {
    int jid = bt * 2 + dir;  // 0..127
    for (int job = jid; job < 576; job += 128) {
      __syncthreads();
      int o = job & 63, by = job >> 6;
      if (by < 8) {
        int t0 = by * 32;
        const float* Wo = W1 + (size_t)o * 32768 + 16384;
        for (int idx = tid; idx < 16384; idx += 256) W1s[idx >> 7][idx & 127] = Wo[idx];
        for (int idx = tid; idx < 4096; idx += 256)
          ls[idx >> 5][idx & 31] = lTw[(idx >> 5) * 256 + t0 + (idx & 31)];
        __syncthreads();
        int c = tid & 127, th = tid >> 7;
        float acc[16];
#pragma unroll
        for (int q = 0; q < 16; ++q) acc[q] = 0.f;
        for (int t2 = 0; t2 < 128; ++t2) {
          float wv = W1s[c][t2];
#pragma unroll
          for (int q = 0; q < 16; ++q) acc[q] += wv * ls[t2][th + 2 * q];
        }
        float* Mo = MT + (size_t)o * 32768;
#pragma unroll
        for (int q = 0; q < 16; ++q) Mo[(t0 + th + 2 * q) * 128 + c] = acc[q];
      } else {
        const float* Wo = W1 + (size_t)o * 32768;
        for (int idx = tid; idx < 16384; idx += 256) W1s[idx >> 7][idx & 127] = Wo[idx];
        for (int idx = tid; idx < 640; idx += 256) ls[idx / 5][idx % 5] = lFw[idx];
        __syncthreads();
        int c = tid & 127, fh = tid >> 7;
        float acc[3] = {0.f, 0.f, 0.f};
        for (int t2 = 0; t2 < 128; ++t2) {
          float wv = W1s[c][t2];
#pragma unroll
          for (int q = 0; q < 3; ++q) {
            int f = fh + 2 * q;
            if (f < 5) acc[q] += wv * ls[t2][f];
          }
        }
#pragma unroll
        for (int q = 0; q < 3; ++q) {
          int f = fh + 2 * q;
          if (f < 5) MF[(size_t)o * 640 + f * 128 + c] = acc[q];
        }
        float s = 0.f;
        for (int idx = tid; idx < 16384; idx += 256) {
          int t2 = idx & 127;
          s += Wo[idx] * lFb[t2] + Wo[16384 + idx] * lTb[t2];
        }
        rs[tid] = s;
        __syncthreads();
        for (int off = 128; off; off >>= 1) {
          if (tid < off) rs[tid] += rs[tid + off];
          __syncthreads();
        }
        if (tid == 0) c0v[o] = l1b[o] + rs[0];
      }
    }
  }
}

// ============ BN stats (T and F in one grid) ============
__global__ __launch_bounds__(256) void kbn_all(
    const u16* __restrict__ gTp, const u16* __restrict__ gFp,
    const float* __restrict__ gamT, const float* __restrict__ betT,
    const float* __restrict__ gamF, const float* __restrict__ betF,
    float* __restrict__ sdT, float* __restrict__ sdF) {
  int bid = blockIdx.x, tid = threadIdx.x;
  const u16* g;
  const float *gam, *bet;
  float* sd;
  int S, t;
  if (bid < 256) {
    g = gTp; S = 256; t = bid; gam = gamT; bet = betT; sd = sdT;
  } else {
    g = gFp; S = 5; t = bid - 256; gam = gamF; bet = betF; sd = sdF;
  }
  float s = 0.f, s2 = 0.f;
  for (int unit = tid; unit < 32768; unit += 256) {
    int b = unit >> 5, c4 = (unit & 31) * 4;
    ushort4 u = *(const ushort4*)(g + ((size_t)b * S + t) * 128 + c4);
    float v0 = __uint_as_float((unsigned)u.x << 16);
    float v1 = __uint_as_float((unsigned)u.y << 16);
    float v2 = __uint_as_float((unsigned)u.z << 16);
    float v3 = __uint_as_float((unsigned)u.w << 16);
    s += v0 + v1 + v2 + v3;
    s2 += v0 * v0 + v1 * v1 + v2 * v2 + v3 * v3;
  }
  __shared__ float rs[256], rq[256];
  rs[tid] = s;
  rq[tid] = s2;
  __syncthreads();
  for (int off = 128; off; off >>= 1) {
    if (tid < off) {
      rs[tid] += rs[tid + off];
      rq[tid] += rq[tid + off];
    }
    __syncthreads();
  }
  if (tid == 0) {
    float inv_n = 1.f / (float)(B_ * C_);
    float m = rs[0] * inv_n;
    float var = rq[0] * inv_n - m * m;
    float inv = 1.f / sqrtf(var + 1e-5f);
    float sc = gam[t] * inv;
    sd[2 * t] = sc;
    sd[2 * t + 1] = bet[t] - m * sc;
  }
}

// ============ kchunk (32-batch/nt=16/17-slot form) ============
__global__ __launch_bounds__(256) void kchunk_all(
    const u16* __restrict__ gTp, const u16* __restrict__ gFp,
    const float* __restrict__ sdT, const float* __restrict__ sdF,
    const float* __restrict__ MT, const float* __restrict__ MF,
    float* __restrict__ part) {
  __shared__ float gs[32][132];
  __shared__ float Ms[64][132];
  int tid = threadIdx.x;
  int b0 = blockIdx.x * 32;
  int by = blockIdx.y;
  const u16* g;
  const float *sd, *M;
  int S, nt, t0, slot;
  if (by < 16) {
    g = gTp; sd = sdT; M = MT; S = 256; nt = 16; t0 = by * 16; slot = by;
  } else {
    g = gFp; sd = sdF; M = MF; S = 5; nt = 5; t0 = 0; slot = 16;
  }
  int ot = tid & 31, bt = tid >> 5;
  float acc[4][2];
#pragma unroll
  for (int i = 0; i < 4; ++i) {
    acc[i][0] = 0.f;
    acc[i][1] = 0.f;
  }
  for (int t = t0; t < t0 + nt; ++t) {
    __syncthreads();
    float sc = sd[2 * t], dd = sd[2 * t + 1];
    for (int idx = tid; idx < 1024; idx += 256) {
      int bb = idx >> 5, c4 = (idx & 31) * 4;
      ushort4 u = *(const ushort4*)(g + ((size_t)(b0 + bb) * S + t) * 128 + c4);
      gs[bb][c4 + 0] = __uint_as_float((unsigned)u.x << 16) * sc + dd;
      gs[bb][c4 + 1] = __uint_as_float((unsigned)u.y << 16) * sc + dd;
      gs[bb][c4 + 2] = __uint_as_float((unsigned)u.z << 16) * sc + dd;
      gs[bb][c4 + 3] = __uint_as_float((unsigned)u.w << 16) * sc + dd;
    }
    for (int idx = tid; idx < 2048; idx += 256) {
      int o = idx >> 5, c4 = (idx & 31) * 4;
      *(float4*)&Ms[o][c4] = *(const float4*)(M + ((size_t)o * S + t) * 128 + c4);
    }
    __syncthreads();
    for (int c = 0; c < 128; c += 4) {
      f32x4 m0 = *(const f32x4*)&Ms[ot][c];
      f32x4 m1 = *(const f32x4*)&Ms[ot + 32][c];
#pragma unroll
      for (int i = 0; i < 4; ++i) {
        f32x4 gv = *(const f32x4*)&gs[bt * 4 + i][c];
        acc[i][0] += gv[0] * m0[0] + gv[1] * m0[1] + gv[2] * m0[2] + gv[3] * m0[3];
        acc[i][1] += gv[0] * m1[0] + gv[1] * m1[1] + gv[2] * m1[2] + gv[3] * m1[3];
      }
    }
  }
#pragma unroll
  for (int i = 0; i < 4; ++i) {
    part[((size_t)slot * 1024 + b0 + bt * 4 + i) * 64 + ot] = acc[i][0];
    part[((size_t)slot * 1024 + b0 + bt * 4 + i) * 64 + ot + 32] = acc[i][1];
  }
}

// ============ finalize ============
__global__ __launch_bounds__(64) void kfin(const float* __restrict__ part,
                                           const float* __restrict__ c0,
                                           const float* __restrict__ l2w,
                                           const float* __restrict__ l2b,
                                           float* __restrict__ outp) {
  int b = blockIdx.x, o = threadIdx.x;
  float y = c0[o];
  for (int s = 0; s < 17; ++s) y += part[((size_t)s * 1024 + b) * 64 + o];
  y = leaky(y);
  __shared__ float a[64];
  a[o] = y;
  __syncthreads();
  if (o < 3) {
    float r = l2b[o];
    for (int j = 0; j < 64; ++j) r += l2w[o * 64 + j] * a[j];
    outp[b * 3 + o] = r;
  }
}

extern "C" void kernel_launch(void* const* d_in, const int* in_sizes, int n_in,
                              void* d_out, int out_size, void* d_ws, size_t ws_size,
                              hipStream_t stream) {
  const float* x_T = (const float*)d_in[0];
  const float* x_F = (const float*)d_in[1];
  const float* A = (const float*)d_in[2];
  const float* gcnw_F = (const float*)d_in[3];
  const float* gFwih_f = (const float*)d_in[4];
  const float* gFwhh_f = (const float*)d_in[5];
  const float* gFbih_f = (const float*)d_in[6];
  const float* gFbhh_f = (const float*)d_in[7];
  const float* gFwih_b = (const float*)d_in[8];
  const float* gFwhh_b = (const float*)d_in[9];
  const float* gFbih_b = (const float*)d_in[10];
  const float* gFbhh_b = (const float*)d_in[11];
  const float* bnFg = (const float*)d_in[12];
  const float* bnFb = (const float*)d_in[13];
  const float* gcnw_T = (const float*)d_in[14];
  const float* gTwih_f = (const float*)d_in[15];
  const float* gTwhh_f = (const float*)d_in[16];
  const float* gTbih_f = (const float*)d_in[17];
  const float* gTbhh_f = (const float*)d_in[18];
  const float* gTwih_b = (const float*)d_in[19];
  const float* gTwhh_b = (const float*)d_in[20];
  const float* gTbih_b = (const float*)d_in[21];
  const float* gTbhh_b = (const float*)d_in[22];
  const float* bnTg = (const float*)d_in[23];
  const float* bnTb = (const float*)d_in[24];
  const float* linF_w = (const float*)d_in[25];
  const float* linF_b = (const float*)d_in[26];
  const float* linT_w = (const float*)d_in[27];
  const float* linT_b = (const float*)d_in[28];
  const float* lin1_w = (const float*)d_in[29];
  const float* lin1_b = (const float*)d_in[30];
  const float* lin2_w = (const float*)d_in[31];
  const float* lin2_b = (const float*)d_in[32];

  char* w8 = (char*)d_ws;
  size_t off = 0;
  auto take = [&](size_t bytes) {
    void* p = w8 + off;
    off += (bytes + 255) & ~(size_t)255;
    return p;
  };
  float* XpT = (float*)take((size_t)1024 * 256 * 64 * 4);
  float* XpF = (float*)take((size_t)1024 * 5 * 64 * 4);
  u16* XfT = (u16*)take((size_t)64 * 256 * 2048 * 2);
  u16* XfF = (u16*)take((size_t)64 * 5 * 2048 * 2);
  u16* gT = (u16*)take((size_t)1024 * 256 * 128 * 2);
  u16* gF = (u16*)take((size_t)1024 * 5 * 128 * 2);
  float* sdT = (float*)take(512 * 4);
  float* sdF = (float*)take(16 * 4);
  float* MT = (float*)take((size_t)64 * 256 * 128 * 4);
  float* MF = (float*)take((size_t)64 * 5 * 128 * 4);
  float* c0 = (float*)take(64 * 4);
  float* part = (float*)take((size_t)17 * 1024 * 64 * 4);

  knorm_xc<<<1024, 256, 0, stream>>>(A, x_T, x_F, gcnw_T, gcnw_F, XpT, XpF);
  kxq_all<<<dim3(64, 66), 256, 0, stream>>>(XpT, XpF, XfT, XfF);
  kgru_all<<<dim3(64, 2, 2), 256, 0, stream>>>(
      XfT, XfF, gTwih_f, gTwhh_f, gTbih_f, gTbhh_f, gTwih_b, gTwhh_b, gTbih_b, gTbhh_b,
      gFwih_f, gFwhh_f, gFbih_f, gFbhh_f, gFwih_b, gFwhh_b, gFbih_b, gFbhh_b, gT, gF,
      lin1_w, linT_w, linF_w, linF_b, linT_b, lin1_b, MT, MF, c0);
  kbn_all<<<261, 256, 0, stream>>>(gT, gF, bnTg, bnTb, bnFg, bnFb, sdT, sdF);
  kchunk_all<<<dim3(32, 17), 256, 0, stream>>>(gT, gF, sdT, sdF, MT, MF, part);
  kfin<<<1024, 64, 0, stream>>>(part, c0, lin2_w, lin2_b, (float*)d_out);
}

// Round 20
// 466.387 us; speedup vs baseline: 1.1383x; 1.0387x over previous
//
#include <hip/hip_runtime.h>

#define B_ 1024
#define N_ 64
#define T_ 256
#define FB_ 5
#define T2_ 128
#define C_ 128  // 2N

typedef unsigned short u16;
typedef __attribute__((ext_vector_type(8))) short bf16x8;
typedef __attribute__((ext_vector_type(4))) float f32x4;

__device__ __forceinline__ float leaky(float x) { return x >= 0.f ? x : 0.01f * x; }
__device__ __forceinline__ float rcpf(float x) { return __builtin_amdgcn_rcpf(x); }
__device__ __forceinline__ float sigm2(float x) { return rcpf(1.f + __expf(-x)); }
__device__ __forceinline__ float tanh2(float x) { return 1.f - 2.f * rcpf(1.f + __expf(2.f * x)); }
__device__ __forceinline__ unsigned bf16_rne(float f) {
  unsigned u = __float_as_uint(f);
  return (u + 0x7FFFu + ((u >> 16) & 1u)) >> 16;
}
// barrier that does NOT drain vmcnt (keeps global prefetch in flight)
__device__ __forceinline__ void block_sync_lds() {
  __builtin_amdgcn_sched_barrier(0);
  asm volatile("s_waitcnt lgkmcnt(0)" ::: "memory");
  __builtin_amdgcn_s_barrier();
  __builtin_amdgcn_sched_barrier(0);
}

#define MFMA_(A, B, C) __builtin_amdgcn_mfma_f32_16x16x32_bf16(A, B, C, 0, 0, 0)

// ============ fused norm_adj + Xc(T) + Xc(F): HsT in LDS; 2 LDS instr / 16 FMA ============
__device__ __forceinline__ void xc_tile(const float (*HsT)[68], float (*xs)[68],
                                        const float* __restrict__ Xb, int S, int t0, float w,
                                        float* __restrict__ Ob, int tid) {
  __syncthreads();
  for (int idx = tid; idx < 4096; idx += 256) {
    int j = idx >> 6, tt = idx & 63;
    xs[j][tt] = (t0 + tt < S) ? Xb[j * S + t0 + tt] : 0.f;
  }
  __syncthreads();
  int i0 = (tid & 15) * 4, tl = (tid >> 4) * 4;
  f32x4 a0 = {0, 0, 0, 0}, a1 = {0, 0, 0, 0}, a2 = {0, 0, 0, 0}, a3 = {0, 0, 0, 0};
#pragma unroll 4
  for (int j = 0; j < 64; ++j) {
    f32x4 hv = *(const f32x4*)&HsT[j][i0];
    f32x4 xv = *(const f32x4*)&xs[j][tl];
    a0 += hv * xv[0];
    a1 += hv * xv[1];
    a2 += hv * xv[2];
    a3 += hv * xv[3];
  }
#define STORE_T(K, AV)                                  \
  {                                                     \
    int t = t0 + tl + K;                                \
    if (t < S) {                                        \
      f32x4 r;                                          \
      _Pragma("unroll") for (int e = 0; e < 4; ++e)     \
          r[e] = leaky(w * AV[e]);                      \
      *(f32x4*)&Ob[(size_t)t * 64 + i0] = r;            \
    }                                                   \
  }
  STORE_T(0, a0)
  STORE_T(1, a1)
  STORE_T(2, a2)
  STORE_T(3, a3)
#undef STORE_T
}

__global__ __launch_bounds__(256) void knorm_xc(
    const float* __restrict__ A, const float* __restrict__ xT, const float* __restrict__ xF,
    const float* __restrict__ wT, const float* __restrict__ wF,
    float* __restrict__ XpT, float* __restrict__ XpF) {
  __shared__ float HsT[64][68];  // HsT[j][i]
  __shared__ float dinv[64];
  __shared__ float xs[64][68];
  int b = blockIdx.x, tid = threadIdx.x;
  const float* Ab = A + (size_t)b * 4096;
  for (int idx = tid; idx < 4096; idx += 256) {
    int i = idx >> 6, j = idx & 63;
    HsT[j][i] = (i == j) ? 1.f : Ab[idx];
  }
  __syncthreads();
  if (tid < 64) {
    float s = 0.f;
    for (int j = 0; j < 64; ++j) s += HsT[j][tid];
    dinv[tid] = 1.f / sqrtf(s);
  }
  __syncthreads();
  for (int idx = tid; idx < 4096; idx += 256) {
    int j = idx >> 6, i = idx & 63;
    HsT[j][i] *= dinv[i] * dinv[j];
  }
  {
    const float* Xb = xT + (size_t)b * 64 * 256;
    float w = wT[0];
    float* Ob = XpT + (size_t)b * 256 * 64;
    for (int t0 = 0; t0 < 256; t0 += 64) xc_tile(HsT, xs, Xb, 256, t0, w, Ob, tid);
  }
  {
    const float* Xb = xF + (size_t)b * 64 * 5;
    float w = wF[0];
    float* Ob = XpF + (size_t)b * 5 * 64;
    xc_tile(HsT, xs, Xb, 5, 0, w, Ob, tid);
  }
}

// ============ repack Xp -> bf16 hi/lo lane-major MFMA B-fragments ============
__global__ __launch_bounds__(256) void kxq_all(const float* __restrict__ XpT,
                                               const float* __restrict__ XpF,
                                               u16* __restrict__ XfT, u16* __restrict__ XfF) {
  __shared__ float xs[4][16][68];
  int bt = blockIdx.x, by = blockIdx.y, tid = threadIdx.x;
  const float* Xp;
  u16* Xf;
  int S, t0;
  if (by < 64) {
    Xp = XpT; Xf = XfT; S = 256; t0 = by * 4;
  } else {
    Xp = XpF; Xf = XfF; S = 5; t0 = (by - 64) * 4;
  }
  for (int idx = tid; idx < 1024; idx += 256) {
    int b_l = idx >> 6, rest = idx & 63, t_l = rest >> 4, c = rest & 15;
    float4 v = {0.f, 0.f, 0.f, 0.f};
    if (t0 + t_l < S)
      v = *(const float4*)(Xp + ((size_t)(bt * 16 + b_l) * S + t0 + t_l) * 64 + c * 4);
    *(float4*)&xs[t_l][b_l][c * 4] = v;
  }
  __syncthreads();
  int t_l = tid >> 6, lane = tid & 63, blo = lane & 15, grp = lane >> 4;
  int t = t0 + t_l;
  if (t >= S) return;
#pragma unroll
  for (int kh = 0; kh < 2; ++kh) {
    const f32x4* src = (const f32x4*)&xs[t_l][blo][kh * 32 + grp * 8];
    f32x4 a0 = src[0], a1 = src[1];
    bf16x8 hi, lo;
#pragma unroll
    for (int e = 0; e < 4; ++e) {
      unsigned h0 = bf16_rne(a0[e]);
      hi[e] = (short)h0;
      lo[e] = (short)bf16_rne(a0[e] - __uint_as_float(h0 << 16));
      unsigned h1 = bf16_rne(a1[e]);
      hi[e + 4] = (short)h1;
      lo[e + 4] = (short)bf16_rne(a1[e] - __uint_as_float(h1 << 16));
    }
    u16* dst = Xf + (size_t)(bt * S + t) * 2048 + (size_t)kh * 1024 + lane * 8;
    *(bf16x8*)dst = hi;
    *(bf16x8*)(dst + 512) = lo;
  }
}

// ============ MFMA bidirectional GRU (T/F), h fed back as plain bf16 ============
// ax keeps full hi/lo x split (off critical path); ah uses 2 products (Whh_hi,Whh_lo)*h.
// + embedded kM on the F-blocks' idle CUs.
__device__ __forceinline__ void axcomp(f32x4 (&AX)[3], const bf16x8 (&XB)[4],
                                       const bf16x8 (&Whi)[3][2], const bf16x8 (&Wlo)[3][2],
                                       const f32x4 (&bI)[3]) {
  AX[0] = bI[0];
  AX[1] = bI[1];
  AX[2] = bI[2];
#pragma unroll
  for (int kh = 0; kh < 2; ++kh) {
    bf16x8 xh = XB[2 * kh], xl = XB[2 * kh + 1];
#pragma unroll
    for (int gi = 0; gi < 3; ++gi) {
      AX[gi] = MFMA_(Whi[gi][kh], xh, AX[gi]);
      AX[gi] = MFMA_(Whi[gi][kh], xl, AX[gi]);
      AX[gi] = MFMA_(Wlo[gi][kh], xh, AX[gi]);
    }
  }
}

__global__ __launch_bounds__(256, 1) void kgru_all(
    const u16* __restrict__ XfT, const u16* __restrict__ XfF,
    const float* __restrict__ Twih_f, const float* __restrict__ Twhh_f,
    const float* __restrict__ Tbih_f, const float* __restrict__ Tbhh_f,
    const float* __restrict__ Twih_b, const float* __restrict__ Twhh_b,
    const float* __restrict__ Tbih_b, const float* __restrict__ Tbhh_b,
    const float* __restrict__ Fwih_f, const float* __restrict__ Fwhh_f,
    const float* __restrict__ Fbih_f, const float* __restrict__ Fbhh_f,
    const float* __restrict__ Fwih_b, const float* __restrict__ Fwhh_b,
    const float* __restrict__ Fbih_b, const float* __restrict__ Fbhh_b,
    u16* __restrict__ gT, u16* __restrict__ gF,
    const float* __restrict__ W1, const float* __restrict__ lTw, const float* __restrict__ lFw,
    const float* __restrict__ lFb, const float* __restrict__ lTb, const float* __restrict__ l1b,
    float* __restrict__ MT, float* __restrict__ MF, float* __restrict__ c0v) {
  __shared__ u16 Hhi[2][16][72];
  __shared__ float W1s[128][129];
  __shared__ float ls[128][32];
  __shared__ float rs[256];
  int tid = threadIdx.x;
  int w = tid >> 6, lane = tid & 63, blo = lane & 15, grp = lane >> 4;
  int bt = blockIdx.x, dir = blockIdx.y, tf = blockIdx.z;
  int S = tf ? 5 : 256;
  const u16* Xf = tf ? XfF : XfT;
  u16* g = tf ? gF : gT;
  const float* wih = tf ? (dir ? Fwih_b : Fwih_f) : (dir ? Twih_b : Twih_f);
  const float* whh = tf ? (dir ? Fwhh_b : Fwhh_f) : (dir ? Twhh_b : Twhh_f);
  const float* bih = tf ? (dir ? Fbih_b : Fbih_f) : (dir ? Tbih_b : Tbih_f);
  const float* bhh = tf ? (dir ? Fbhh_b : Fbhh_f) : (dir ? Tbhh_b : Tbhh_f);

  for (int idx = tid; idx < 2 * 16 * 72; idx += 256) {
    ((u16*)Hhi)[idx] = 0;
  }

  bf16x8 Wih_hi[3][2], Wih_lo[3][2], Whh_hi[3][2], Whh_lo[3][2];
#pragma unroll
  for (int gi = 0; gi < 3; ++gi) {
    int k = (gi * 4 + w) * 16 + blo;
#pragma unroll
    for (int kh = 0; kh < 2; ++kh) {
      int j0 = kh * 32 + grp * 8;
#pragma unroll
      for (int m = 0; m < 2; ++m) {
        const float* src = (m ? whh : wih) + (size_t)k * 64 + j0;
        f32x4 a0 = *(const f32x4*)src;
        f32x4 a1 = *(const f32x4*)(src + 4);
        bf16x8 hi, lo;
#pragma unroll
        for (int e = 0; e < 4; ++e) {
          unsigned h0 = bf16_rne(a0[e]);
          hi[e] = (short)h0;
          lo[e] = (short)bf16_rne(a0[e] - __uint_as_float(h0 << 16));
          unsigned h1 = bf16_rne(a1[e]);
          hi[e + 4] = (short)h1;
          lo[e + 4] = (short)bf16_rne(a1[e] - __uint_as_float(h1 << 16));
        }
        if (m) {
          Whh_hi[gi][kh] = hi;
          Whh_lo[gi][kh] = lo;
        } else {
          Wih_hi[gi][kh] = hi;
          Wih_lo[gi][kh] = lo;
        }
      }
    }
  }
  f32x4 bI[3], bH[3];
#pragma unroll
  for (int gi = 0; gi < 3; ++gi) {
    int k0 = (gi * 4 + w) * 16 + 4 * grp;
    bI[gi] = *(const f32x4*)(bih + k0);
    bH[gi] = *(const f32x4*)(bhh + k0);
  }

  float ho[4] = {0.f, 0.f, 0.f, 0.f};
  int j0q = 16 * w + 4 * grp;
  const u16* xbase = Xf + (size_t)bt * S * 2048 + lane * 8;
  long long sstep = dir ? -4096LL : 4096LL;
  long long gstep = dir ? -256LL : 256LL;

  bf16x8 x0[4], x1[4], x2[4], x3[4];
#define LOADX(DST, TR)                            \
  {                                               \
    const u16* xp = xbase + (size_t)(TR) * 2048;  \
    DST[0] = *(const bf16x8*)(xp);                \
    DST[1] = *(const bf16x8*)(xp + 512);          \
    DST[2] = *(const bf16x8*)(xp + 1024);         \
    DST[3] = *(const bf16x8*)(xp + 1536);         \
  }
  LOADX(x0, dir ? (S - 1) : 0)
  if (S > 1) LOADX(x1, dir ? (S - 2) : 1)
  if (S > 2) LOADX(x2, dir ? (S - 3) : 2)
  const u16* xw = xbase + (size_t)(dir ? (S >= 4 ? S - 4 : 0) : 3) * 2048;
  u16* gp = g + ((size_t)(bt * 16 + blo) * S + (dir ? S - 1 : 0)) * 128 + dir * 64 + j0q;

  f32x4 axA[3], axB[3];
  axcomp(axA, x0, Wih_hi, Wih_lo, bI);
  block_sync_lds();

#define GSTEP(KK, XAX, XLD, AXC, AXN, PR, PW)                                        \
  {                                                                                  \
    int t = tbase + KK;                                                              \
    if (t < S) {                                                                     \
      bf16x8 h0h = *(const bf16x8*)&Hhi[PR][blo][grp * 8];                           \
      bf16x8 h1h = *(const bf16x8*)&Hhi[PR][blo][32 + grp * 8];                      \
      if (t + 3 < S) {                                                               \
        XLD[0] = *(const bf16x8*)(xw);                                               \
        XLD[1] = *(const bf16x8*)(xw + 512);                                         \
        XLD[2] = *(const bf16x8*)(xw + 1024);                                        \
        XLD[3] = *(const bf16x8*)(xw + 1536);                                        \
        xw = (const u16*)((const char*)xw + sstep);                                  \
      }                                                                              \
      if (t + 1 < S) axcomp(AXN, XAX, Wih_hi, Wih_lo, bI);                           \
      f32x4 ahr = bH[0], ahz = bH[1], ahn = bH[2];                                   \
      ahr = MFMA_(Whh_hi[0][0], h0h, ahr);                                           \
      ahr = MFMA_(Whh_lo[0][0], h0h, ahr);                                           \
      ahz = MFMA_(Whh_hi[1][0], h0h, ahz);                                           \
      ahz = MFMA_(Whh_lo[1][0], h0h, ahz);                                           \
      ahn = MFMA_(Whh_hi[2][0], h0h, ahn);                                           \
      ahn = MFMA_(Whh_lo[2][0], h0h, ahn);                                           \
      ahr = MFMA_(Whh_hi[0][1], h1h, ahr);                                           \
      ahr = MFMA_(Whh_lo[0][1], h1h, ahr);                                           \
      ahz = MFMA_(Whh_hi[1][1], h1h, ahz);                                           \
      ahz = MFMA_(Whh_lo[1][1], h1h, ahz);                                           \
      ahn = MFMA_(Whh_hi[2][1], h1h, ahn);                                           \
      ahn = MFMA_(Whh_lo[2][1], h1h, ahn);                                           \
      u16 hi_u[4];                                                                   \
      _Pragma("unroll") for (int u = 0; u < 4; ++u) {                                \
        float r = sigm2(AXC[0][u] + ahr[u]);                                         \
        float z = sigm2(AXC[1][u] + ahz[u]);                                         \
        float n = tanh2(AXC[2][u] + r * ahn[u]);                                     \
        float h = n + z * (ho[u] - n);                                               \
        ho[u] = h;                                                                   \
        hi_u[u] = (u16)((__float_as_uint(h) + 0x8000u) >> 16);                       \
      }                                                                              \
      ushort4 h4;                                                                    \
      h4.x = hi_u[0]; h4.y = hi_u[1]; h4.z = hi_u[2]; h4.w = hi_u[3];                \
      *(ushort4*)&Hhi[PW][blo][j0q] = h4;                                            \
      *(ushort4*)gp = h4;                                                            \
      gp = (u16*)((char*)gp + gstep);                                                \
      block_sync_lds();                                                              \
    }                                                                                \
  }

  for (int tbase = 0; tbase < S; tbase += 4) {
    GSTEP(0, x1, x3, axA, axB, 0, 1)
    GSTEP(1, x2, x0, axB, axA, 1, 0)
    GSTEP(2, x3, x1, axA, axB, 0, 1)
    GSTEP(3, x0, x2, axB, axA, 1, 0)
  }
#undef GSTEP
#undef LOADX

  // ---- embedded kM: F-blocks (tf==1) run the MT/MF/c0 jobs on otherwise-idle CUs ----
  if (tf == 1) {
    int jid = bt * 2 + dir;  // 0..127
    for (int job = jid; job < 576; job += 128) {
      __syncthreads();
      int o = job & 63, by = job >> 6;
      if (by < 8) {
        int t0 = by * 32;
        const float* Wo = W1 + (size_t)o * 32768 + 16384;
        for (int idx = tid; idx < 16384; idx += 256) W1s[idx >> 7][idx & 127] = Wo[idx];
        for (int idx = tid; idx < 4096; idx += 256)
          ls[idx >> 5][idx & 31] = lTw[(idx >> 5) * 256 + t0 + (idx & 31)];
        __syncthreads();
        int c = tid & 127, th = tid >> 7;
        float acc[16];
#pragma unroll
        for (int q = 0; q < 16; ++q) acc[q] = 0.f;
        for (int t2 = 0; t2 < 128; ++t2) {
          float wv = W1s[c][t2];
#pragma unroll
          for (int q = 0; q < 16; ++q) acc[q] += wv * ls[t2][th + 2 * q];
        }
        float* Mo = MT + (size_t)o * 32768;
#pragma unroll
        for (int q = 0; q < 16; ++q) Mo[(t0 + th + 2 * q) * 128 + c] = acc[q];
      } else {
        const float* Wo = W1 + (size_t)o * 32768;
        for (int idx = tid; idx < 16384; idx += 256) W1s[idx >> 7][idx & 127] = Wo[idx];
        for (int idx = tid; idx < 640; idx += 256) ls[idx / 5][idx % 5] = lFw[idx];
        __syncthreads();
        int c = tid & 127, fh = tid >> 7;
        float acc[3] = {0.f, 0.f, 0.f};
        for (int t2 = 0; t2 < 128; ++t2) {
          float wv = W1s[c][t2];
#pragma unroll
          for (int q = 0; q < 3; ++q) {
            int f = fh + 2 * q;
            if (f < 5) acc[q] += wv * ls[t2][f];
          }
        }
#pragma unroll
        for (int q = 0; q < 3; ++q) {
          int f = fh + 2 * q;
          if (f < 5) MF[(size_t)o * 640 + f * 128 + c] = acc[q];
        }
        float s = 0.f;
        for (int idx = tid; idx < 16384; idx += 256) {
          int t2 = idx & 127;
          s += Wo[idx] * lFb[t2] + Wo[16384 + idx] * lTb[t2];
        }
        rs[tid] = s;
        __syncthreads();
        for (int off = 128; off; off >>= 1) {
          if (tid < off) rs[tid] += rs[tid + off];
          __syncthreads();
        }
        if (tid == 0) c0v[o] = l1b[o] + rs[0];
      }
    }
  }
}

// ============ BN stats (T and F in one grid) ============
__global__ __launch_bounds__(256) void kbn_all(
    const u16* __restrict__ gTp, const u16* __restrict__ gFp,
    const float* __restrict__ gamT, const float* __restrict__ betT,
    const float* __restrict__ gamF, const float* __restrict__ betF,
    float* __restrict__ sdT, float* __restrict__ sdF) {
  int bid = blockIdx.x, tid = threadIdx.x;
  const u16* g;
  const float *gam, *bet;
  float* sd;
  int S, t;
  if (bid < 256) {
    g = gTp; S = 256; t = bid; gam = gamT; bet = betT; sd = sdT;
  } else {
    g = gFp; S = 5; t = bid - 256; gam = gamF; bet = betF; sd = sdF;
  }
  float s = 0.f, s2 = 0.f;
  for (int unit = tid; unit < 32768; unit += 256) {
    int b = unit >> 5, c4 = (unit & 31) * 4;
    ushort4 u = *(const ushort4*)(g + ((size_t)b * S + t) * 128 + c4);
    float v0 = __uint_as_float((unsigned)u.x << 16);
    float v1 = __uint_as_float((unsigned)u.y << 16);
    float v2 = __uint_as_float((unsigned)u.z << 16);
    float v3 = __uint_as_float((unsigned)u.w << 16);
    s += v0 + v1 + v2 + v3;
    s2 += v0 * v0 + v1 * v1 + v2 * v2 + v3 * v3;
  }
  __shared__ float rs[256], rq[256];
  rs[tid] = s;
  rq[tid] = s2;
  __syncthreads();
  for (int off = 128; off; off >>= 1) {
    if (tid < off) {
      rs[tid] += rs[tid + off];
      rq[tid] += rq[tid + off];
    }
    __syncthreads();
  }
  if (tid == 0) {
    float inv_n = 1.f / (float)(B_ * C_);
    float m = rs[0] * inv_n;
    float var = rq[0] * inv_n - m * m;
    float inv = 1.f / sqrtf(var + 1e-5f);
    float sc = gam[t] * inv;
    sd[2 * t] = sc;
    sd[2 * t + 1] = bet[t] - m * sc;
  }
}

// ============ kchunk (32-batch/nt=16/17-slot form) ============
__global__ __launch_bounds__(256) void kchunk_all(
    const u16* __restrict__ gTp, const u16* __restrict__ gFp,
    const float* __restrict__ sdT, const float* __restrict__ sdF,
    const float* __restrict__ MT, const float* __restrict__ MF,
    float* __restrict__ part) {
  __shared__ float gs[32][132];
  __shared__ float Ms[64][132];
  int tid = threadIdx.x;
  int b0 = blockIdx.x * 32;
  int by = blockIdx.y;
  const u16* g;
  const float *sd, *M;
  int S, nt, t0, slot;
  if (by < 16) {
    g = gTp; sd = sdT; M = MT; S = 256; nt = 16; t0 = by * 16; slot = by;
  } else {
    g = gFp; sd = sdF; M = MF; S = 5; nt = 5; t0 = 0; slot = 16;
  }
  int ot = tid & 31, bt = tid >> 5;
  float acc[4][2];
#pragma unroll
  for (int i = 0; i < 4; ++i) {
    acc[i][0] = 0.f;
    acc[i][1] = 0.f;
  }
  for (int t = t0; t < t0 + nt; ++t) {
    __syncthreads();
    float sc = sd[2 * t], dd = sd[2 * t + 1];
    for (int idx = tid; idx < 1024; idx += 256) {
      int bb = idx >> 5, c4 = (idx & 31) * 4;
      ushort4 u = *(const ushort4*)(g + ((size_t)(b0 + bb) * S + t) * 128 + c4);
      gs[bb][c4 + 0] = __uint_as_float((unsigned)u.x << 16) * sc + dd;
      gs[bb][c4 + 1] = __uint_as_float((unsigned)u.y << 16) * sc + dd;
      gs[bb][c4 + 2] = __uint_as_float((unsigned)u.z << 16) * sc + dd;
      gs[bb][c4 + 3] = __uint_as_float((unsigned)u.w << 16) * sc + dd;
    }
    for (int idx = tid; idx < 2048; idx += 256) {
      int o = idx >> 5, c4 = (idx & 31) * 4;
      *(float4*)&Ms[o][c4] = *(const float4*)(M + ((size_t)o * S + t) * 128 + c4);
    }
    __syncthreads();
    for (int c = 0; c < 128; c += 4) {
      f32x4 m0 = *(const f32x4*)&Ms[ot][c];
      f32x4 m1 = *(const f32x4*)&Ms[ot + 32][c];
#pragma unroll
      for (int i = 0; i < 4; ++i) {
        f32x4 gv = *(const f32x4*)&gs[bt * 4 + i][c];
        acc[i][0] += gv[0] * m0[0] + gv[1] * m0[1] + gv[2] * m0[2] + gv[3] * m0[3];
        acc[i][1] += gv[0] * m1[0] + gv[1] * m1[1] + gv[2] * m1[2] + gv[3] * m1[3];
      }
    }
  }
#pragma unroll
  for (int i = 0; i < 4; ++i) {
    part[((size_t)slot * 1024 + b0 + bt * 4 + i) * 64 + ot] = acc[i][0];
    part[((size_t)slot * 1024 + b0 + bt * 4 + i) * 64 + ot + 32] = acc[i][1];
  }
}

// ============ finalize ============
__global__ __launch_bounds__(64) void kfin(const float* __restrict__ part,
                                           const float* __restrict__ c0,
                                           const float* __restrict__ l2w,
                                           const float* __restrict__ l2b,
                                           float* __restrict__ outp) {
  int b = blockIdx.x, o = threadIdx.x;
  float y = c0[o];
  for (int s = 0; s < 17; ++s) y += part[((size_t)s * 1024 + b) * 64 + o];
  y = leaky(y);
  __shared__ float a[64];
  a[o] = y;
  __syncthreads();
  if (o < 3) {
    float r = l2b[o];
    for (int j = 0; j < 64; ++j) r += l2w[o * 64 + j] * a[j];
    outp[b * 3 + o] = r;
  }
}

extern "C" void kernel_launch(void* const* d_in, const int* in_sizes, int n_in,
                              void* d_out, int out_size, void* d_ws, size_t ws_size,
                              hipStream_t stream) {
  const float* x_T = (const float*)d_in[0];
  const float* x_F = (const float*)d_in[1];
  const float* A = (const float*)d_in[2];
  const float* gcnw_F = (const float*)d_in[3];
  const float* gFwih_f = (const float*)d_in[4];
  const float* gFwhh_f = (const float*)d_in[5];
  const float* gFbih_f = (const float*)d_in[6];
  const float* gFbhh_f = (const float*)d_in[7];
  const float* gFwih_b = (const float*)d_in[8];
  const float* gFwhh_b = (const float*)d_in[9];
  const float* gFbih_b = (const float*)d_in[10];
  const float* gFbhh_b = (const float*)d_in[11];
  const float* bnFg = (const float*)d_in[12];
  const float* bnFb = (const float*)d_in[13];
  const float* gcnw_T = (const float*)d_in[14];
  const float* gTwih_f = (const float*)d_in[15];
  const float* gTwhh_f = (const float*)d_in[16];
  const float* gTbih_f = (const float*)d_in[17];
  const float* gTbhh_f = (const float*)d_in[18];
  const float* gTwih_b = (const float*)d_in[19];
  const float* gTwhh_b = (const float*)d_in[20];
  const float* gTbih_b = (const float*)d_in[21];
  const float* gTbhh_b = (const float*)d_in[22];
  const float* bnTg = (const float*)d_in[23];
  const float* bnTb = (const float*)d_in[24];
  const float* linF_w = (const float*)d_in[25];
  const float* linF_b = (const float*)d_in[26];
  const float* linT_w = (const float*)d_in[27];
  const float* linT_b = (const float*)d_in[28];
  const float* lin1_w = (const float*)d_in[29];
  const float* lin1_b = (const float*)d_in[30];
  const float* lin2_w = (const float*)d_in[31];
  const float* lin2_b = (const float*)d_in[32];

  char* w8 = (char*)d_ws;
  size_t off = 0;
  auto take = [&](size_t bytes) {
    void* p = w8 + off;
    off += (bytes + 255) & ~(size_t)255;
    return p;
  };
  float* XpT = (float*)take((size_t)1024 * 256 * 64 * 4);
  float* XpF = (float*)take((size_t)1024 * 5 * 64 * 4);
  u16* XfT = (u16*)take((size_t)64 * 256 * 2048 * 2);
  u16* XfF = (u16*)take((size_t)64 * 5 * 2048 * 2);
  u16* gT = (u16*)take((size_t)1024 * 256 * 128 * 2);
  u16* gF = (u16*)take((size_t)1024 * 5 * 128 * 2);
  float* sdT = (float*)take(512 * 4);
  float* sdF = (float*)take(16 * 4);
  float* MT = (float*)take((size_t)64 * 256 * 128 * 4);
  float* MF = (float*)take((size_t)64 * 5 * 128 * 4);
  float* c0 = (float*)take(64 * 4);
  float* part = (float*)take((size_t)17 * 1024 * 64 * 4);

  knorm_xc<<<1024, 256, 0, stream>>>(A, x_T, x_F, gcnw_T, gcnw_F, XpT, XpF);
  kxq_all<<<dim3(64, 66), 256, 0, stream>>>(XpT, XpF, XfT, XfF);
  kgru_all<<<dim3(64, 2, 2), 256, 0, stream>>>(
      XfT, XfF, gTwih_f, gTwhh_f, gTbih_f, gTbhh_f, gTwih_b, gTwhh_b, gTbih_b, gTbhh_b,
      gFwih_f, gFwhh_f, gFbih_f, gFbhh_f, gFwih_b, gFwhh_b, gFbih_b, gFbhh_b, gT, gF,
      lin1_w, linT_w, linF_w, linF_b, linT_b, lin1_b, MT, MF, c0);
  kbn_all<<<261, 256, 0, stream>>>(gT, gF, bnTg, bnTb, bnFg, bnFb, sdT, sdF);
  kchunk_all<<<dim3(32, 17), 256, 0, stream>>>(gT, gF, sdT, sdF, MT, MF, part);
  kfin<<<1024, 64, 0, stream>>>(part, c0, lin2_w, lin2_b, (float*)d_out);
}

// Round 21
// 444.025 us; speedup vs baseline: 1.1956x; 1.0504x over previous
//
#include <hip/hip_runtime.h>

#define B_ 1024
#define N_ 64
#define T_ 256
#define FB_ 5
#define T2_ 128
#define C_ 128  // 2N

typedef unsigned short u16;
typedef __attribute__((ext_vector_type(8))) short bf16x8;
typedef __attribute__((ext_vector_type(4))) float f32x4;

__device__ __forceinline__ float leaky(float x) { return x >= 0.f ? x : 0.01f * x; }
__device__ __forceinline__ float rcpf(float x) { return __builtin_amdgcn_rcpf(x); }
__device__ __forceinline__ float sigm2(float x) { return rcpf(1.f + __expf(-x)); }
__device__ __forceinline__ float tanh2(float x) { return 1.f - 2.f * rcpf(1.f + __expf(2.f * x)); }
__device__ __forceinline__ unsigned bf16_rne(float f) {
  unsigned u = __float_as_uint(f);
  return (u + 0x7FFFu + ((u >> 16) & 1u)) >> 16;
}
// barrier that does NOT drain vmcnt (keeps global prefetch in flight)
__device__ __forceinline__ void block_sync_lds() {
  __builtin_amdgcn_sched_barrier(0);
  asm volatile("s_waitcnt lgkmcnt(0)" ::: "memory");
  __builtin_amdgcn_s_barrier();
  __builtin_amdgcn_sched_barrier(0);
}

#define MFMA_(A, B, C) __builtin_amdgcn_mfma_f32_16x16x32_bf16(A, B, C, 0, 0, 0)

// ============ fused norm_adj + Xc(T) + Xc(F): HsT in LDS; 2 LDS instr / 16 FMA ============
__device__ __forceinline__ void xc_tile(const float (*HsT)[68], float (*xs)[68],
                                        const float* __restrict__ Xb, int S, int t0, float w,
                                        float* __restrict__ Ob, int tid) {
  __syncthreads();
  for (int idx = tid; idx < 4096; idx += 256) {
    int j = idx >> 6, tt = idx & 63;
    xs[j][tt] = (t0 + tt < S) ? Xb[j * S + t0 + tt] : 0.f;
  }
  __syncthreads();
  int i0 = (tid & 15) * 4, tl = (tid >> 4) * 4;
  f32x4 a0 = {0, 0, 0, 0}, a1 = {0, 0, 0, 0}, a2 = {0, 0, 0, 0}, a3 = {0, 0, 0, 0};
#pragma unroll 4
  for (int j = 0; j < 64; ++j) {
    f32x4 hv = *(const f32x4*)&HsT[j][i0];
    f32x4 xv = *(const f32x4*)&xs[j][tl];
    a0 += hv * xv[0];
    a1 += hv * xv[1];
    a2 += hv * xv[2];
    a3 += hv * xv[3];
  }
#define STORE_T(K, AV)                                  \
  {                                                     \
    int t = t0 + tl + K;                                \
    if (t < S) {                                        \
      f32x4 r;                                          \
      _Pragma("unroll") for (int e = 0; e < 4; ++e)     \
          r[e] = leaky(w * AV[e]);                      \
      *(f32x4*)&Ob[(size_t)t * 64 + i0] = r;            \
    }                                                   \
  }
  STORE_T(0, a0)
  STORE_T(1, a1)
  STORE_T(2, a2)
  STORE_T(3, a3)
#undef STORE_T
}

__global__ __launch_bounds__(256) void knorm_xc(
    const float* __restrict__ A, const float* __restrict__ xT, const float* __restrict__ xF,
    const float* __restrict__ wT, const float* __restrict__ wF,
    float* __restrict__ XpT, float* __restrict__ XpF) {
  __shared__ float HsT[64][68];  // HsT[j][i]
  __shared__ float dinv[64];
  __shared__ float xs[64][68];
  int b = blockIdx.x, tid = threadIdx.x;
  const float* Ab = A + (size_t)b * 4096;
  for (int idx = tid; idx < 4096; idx += 256) {
    int i = idx >> 6, j = idx & 63;
    HsT[j][i] = (i == j) ? 1.f : Ab[idx];
  }
  __syncthreads();
  if (tid < 64) {
    float s = 0.f;
    for (int j = 0; j < 64; ++j) s += HsT[j][tid];
    dinv[tid] = 1.f / sqrtf(s);
  }
  __syncthreads();
  for (int idx = tid; idx < 4096; idx += 256) {
    int j = idx >> 6, i = idx & 63;
    HsT[j][i] *= dinv[i] * dinv[j];
  }
  {
    const float* Xb = xT + (size_t)b * 64 * 256;
    float w = wT[0];
    float* Ob = XpT + (size_t)b * 256 * 64;
    for (int t0 = 0; t0 < 256; t0 += 64) xc_tile(HsT, xs, Xb, 256, t0, w, Ob, tid);
  }
  {
    const float* Xb = xF + (size_t)b * 64 * 5;
    float w = wF[0];
    float* Ob = XpF + (size_t)b * 5 * 64;
    xc_tile(HsT, xs, Xb, 5, 0, w, Ob, tid);
  }
}

// ============ repack Xp -> bf16 hi/lo lane-major MFMA B-fragments ============
__global__ __launch_bounds__(256) void kxq_all(const float* __restrict__ XpT,
                                               const float* __restrict__ XpF,
                                               u16* __restrict__ XfT, u16* __restrict__ XfF) {
  __shared__ float xs[4][16][68];
  int bt = blockIdx.x, by = blockIdx.y, tid = threadIdx.x;
  const float* Xp;
  u16* Xf;
  int S, t0;
  if (by < 64) {
    Xp = XpT; Xf = XfT; S = 256; t0 = by * 4;
  } else {
    Xp = XpF; Xf = XfF; S = 5; t0 = (by - 64) * 4;
  }
  for (int idx = tid; idx < 1024; idx += 256) {
    int b_l = idx >> 6, rest = idx & 63, t_l = rest >> 4, c = rest & 15;
    float4 v = {0.f, 0.f, 0.f, 0.f};
    if (t0 + t_l < S)
      v = *(const float4*)(Xp + ((size_t)(bt * 16 + b_l) * S + t0 + t_l) * 64 + c * 4);
    *(float4*)&xs[t_l][b_l][c * 4] = v;
  }
  __syncthreads();
  int t_l = tid >> 6, lane = tid & 63, blo = lane & 15, grp = lane >> 4;
  int t = t0 + t_l;
  if (t >= S) return;
#pragma unroll
  for (int kh = 0; kh < 2; ++kh) {
    const f32x4* src = (const f32x4*)&xs[t_l][blo][kh * 32 + grp * 8];
    f32x4 a0 = src[0], a1 = src[1];
    bf16x8 hi, lo;
#pragma unroll
    for (int e = 0; e < 4; ++e) {
      unsigned h0 = bf16_rne(a0[e]);
      hi[e] = (short)h0;
      lo[e] = (short)bf16_rne(a0[e] - __uint_as_float(h0 << 16));
      unsigned h1 = bf16_rne(a1[e]);
      hi[e + 4] = (short)h1;
      lo[e + 4] = (short)bf16_rne(a1[e] - __uint_as_float(h1 << 16));
    }
    u16* dst = Xf + (size_t)(bt * S + t) * 2048 + (size_t)kh * 1024 + lane * 8;
    *(bf16x8*)dst = hi;
    *(bf16x8*)(dst + 512) = lo;
  }
}

// ============ MFMA bidirectional GRU (T/F), bf16 h feedback, bf16-rounded weights ============
// ax: Whi*(xh + xl) -> 12 MFMAs; ah: Whh_hi*h -> 6 MFMAs (2-deep chain per gate).
// + embedded kM on the F-blocks' idle CUs.
__device__ __forceinline__ void axcomp(f32x4 (&AX)[3], const bf16x8 (&XB)[4],
                                       const bf16x8 (&Whi)[3][2], const f32x4 (&bI)[3]) {
  AX[0] = bI[0];
  AX[1] = bI[1];
  AX[2] = bI[2];
#pragma unroll
  for (int kh = 0; kh < 2; ++kh) {
    bf16x8 xh = XB[2 * kh], xl = XB[2 * kh + 1];
#pragma unroll
    for (int gi = 0; gi < 3; ++gi) {
      AX[gi] = MFMA_(Whi[gi][kh], xh, AX[gi]);
      AX[gi] = MFMA_(Whi[gi][kh], xl, AX[gi]);
    }
  }
}

__global__ __launch_bounds__(256, 1) void kgru_all(
    const u16* __restrict__ XfT, const u16* __restrict__ XfF,
    const float* __restrict__ Twih_f, const float* __restrict__ Twhh_f,
    const float* __restrict__ Tbih_f, const float* __restrict__ Tbhh_f,
    const float* __restrict__ Twih_b, const float* __restrict__ Twhh_b,
    const float* __restrict__ Tbih_b, const float* __restrict__ Tbhh_b,
    const float* __restrict__ Fwih_f, const float* __restrict__ Fwhh_f,
    const float* __restrict__ Fbih_f, const float* __restrict__ Fbhh_f,
    const float* __restrict__ Fwih_b, const float* __restrict__ Fwhh_b,
    const float* __restrict__ Fbih_b, const float* __restrict__ Fbhh_b,
    u16* __restrict__ gT, u16* __restrict__ gF,
    const float* __restrict__ W1, const float* __restrict__ lTw, const float* __restrict__ lFw,
    const float* __restrict__ lFb, const float* __restrict__ lTb, const float* __restrict__ l1b,
    float* __restrict__ MT, float* __restrict__ MF, float* __restrict__ c0v) {
  __shared__ u16 Hhi[2][16][72];
  __shared__ float W1s[128][129];
  __shared__ float ls[128][32];
  __shared__ float rs[256];
  int tid = threadIdx.x;
  int w = tid >> 6, lane = tid & 63, blo = lane & 15, grp = lane >> 4;
  int bt = blockIdx.x, dir = blockIdx.y, tf = blockIdx.z;
  int S = tf ? 5 : 256;
  const u16* Xf = tf ? XfF : XfT;
  u16* g = tf ? gF : gT;
  const float* wih = tf ? (dir ? Fwih_b : Fwih_f) : (dir ? Twih_b : Twih_f);
  const float* whh = tf ? (dir ? Fwhh_b : Fwhh_f) : (dir ? Twhh_b : Twhh_f);
  const float* bih = tf ? (dir ? Fbih_b : Fbih_f) : (dir ? Tbih_b : Tbih_f);
  const float* bhh = tf ? (dir ? Fbhh_b : Fbhh_f) : (dir ? Tbhh_b : Tbhh_f);

  for (int idx = tid; idx < 2 * 16 * 72; idx += 256) {
    ((u16*)Hhi)[idx] = 0;
  }

  // bf16-rounded weight fragments (no lo compensation)
  bf16x8 Wih_hi[3][2], Whh_hi[3][2];
#pragma unroll
  for (int gi = 0; gi < 3; ++gi) {
    int k = (gi * 4 + w) * 16 + blo;
#pragma unroll
    for (int kh = 0; kh < 2; ++kh) {
      int j0 = kh * 32 + grp * 8;
#pragma unroll
      for (int m = 0; m < 2; ++m) {
        const float* src = (m ? whh : wih) + (size_t)k * 64 + j0;
        f32x4 a0 = *(const f32x4*)src;
        f32x4 a1 = *(const f32x4*)(src + 4);
        bf16x8 hi;
#pragma unroll
        for (int e = 0; e < 4; ++e) {
          hi[e] = (short)bf16_rne(a0[e]);
          hi[e + 4] = (short)bf16_rne(a1[e]);
        }
        if (m) Whh_hi[gi][kh] = hi;
        else Wih_hi[gi][kh] = hi;
      }
    }
  }
  f32x4 bI[3], bH[3];
#pragma unroll
  for (int gi = 0; gi < 3; ++gi) {
    int k0 = (gi * 4 + w) * 16 + 4 * grp;
    bI[gi] = *(const f32x4*)(bih + k0);
    bH[gi] = *(const f32x4*)(bhh + k0);
  }

  float ho[4] = {0.f, 0.f, 0.f, 0.f};
  int j0q = 16 * w + 4 * grp;
  const u16* xbase = Xf + (size_t)bt * S * 2048 + lane * 8;
  long long sstep = dir ? -4096LL : 4096LL;
  long long gstep = dir ? -256LL : 256LL;

  bf16x8 x0[4], x1[4], x2[4], x3[4];
#define LOADX(DST, TR)                            \
  {                                               \
    const u16* xp = xbase + (size_t)(TR) * 2048;  \
    DST[0] = *(const bf16x8*)(xp);                \
    DST[1] = *(const bf16x8*)(xp + 512);          \
    DST[2] = *(const bf16x8*)(xp + 1024);         \
    DST[3] = *(const bf16x8*)(xp + 1536);         \
  }
  LOADX(x0, dir ? (S - 1) : 0)
  if (S > 1) LOADX(x1, dir ? (S - 2) : 1)
  if (S > 2) LOADX(x2, dir ? (S - 3) : 2)
  const u16* xw = xbase + (size_t)(dir ? (S >= 4 ? S - 4 : 0) : 3) * 2048;
  u16* gp = g + ((size_t)(bt * 16 + blo) * S + (dir ? S - 1 : 0)) * 128 + dir * 64 + j0q;

  f32x4 axA[3], axB[3];
  axcomp(axA, x0, Wih_hi, bI);
  block_sync_lds();

#define GSTEP(KK, XAX, XLD, AXC, AXN, PR, PW)                                        \
  {                                                                                  \
    int t = tbase + KK;                                                              \
    if (t < S) {                                                                     \
      bf16x8 h0h = *(const bf16x8*)&Hhi[PR][blo][grp * 8];                           \
      bf16x8 h1h = *(const bf16x8*)&Hhi[PR][blo][32 + grp * 8];                      \
      if (t + 3 < S) {                                                               \
        XLD[0] = *(const bf16x8*)(xw);                                               \
        XLD[1] = *(const bf16x8*)(xw + 512);                                         \
        XLD[2] = *(const bf16x8*)(xw + 1024);                                        \
        XLD[3] = *(const bf16x8*)(xw + 1536);                                        \
        xw = (const u16*)((const char*)xw + sstep);                                  \
      }                                                                              \
      if (t + 1 < S) axcomp(AXN, XAX, Wih_hi, bI);                                   \
      f32x4 ahr = bH[0], ahz = bH[1], ahn = bH[2];                                   \
      ahr = MFMA_(Whh_hi[0][0], h0h, ahr);                                           \
      ahz = MFMA_(Whh_hi[1][0], h0h, ahz);                                           \
      ahn = MFMA_(Whh_hi[2][0], h0h, ahn);                                           \
      ahr = MFMA_(Whh_hi[0][1], h1h, ahr);                                           \
      ahz = MFMA_(Whh_hi[1][1], h1h, ahz);                                           \
      ahn = MFMA_(Whh_hi[2][1], h1h, ahn);                                           \
      u16 hi_u[4];                                                                   \
      _Pragma("unroll") for (int u = 0; u < 4; ++u) {                                \
        float r = sigm2(AXC[0][u] + ahr[u]);                                         \
        float z = sigm2(AXC[1][u] + ahz[u]);                                         \
        float n = tanh2(AXC[2][u] + r * ahn[u]);                                     \
        float h = n + z * (ho[u] - n);                                               \
        ho[u] = h;                                                                   \
        hi_u[u] = (u16)((__float_as_uint(h) + 0x8000u) >> 16);                       \
      }                                                                              \
      ushort4 h4;                                                                    \
      h4.x = hi_u[0]; h4.y = hi_u[1]; h4.z = hi_u[2]; h4.w = hi_u[3];                \
      *(ushort4*)&Hhi[PW][blo][j0q] = h4;                                            \
      *(ushort4*)gp = h4;                                                            \
      gp = (u16*)((char*)gp + gstep);                                                \
      block_sync_lds();                                                              \
    }                                                                                \
  }

  for (int tbase = 0; tbase < S; tbase += 4) {
    GSTEP(0, x1, x3, axA, axB, 0, 1)
    GSTEP(1, x2, x0, axB, axA, 1, 0)
    GSTEP(2, x3, x1, axA, axB, 0, 1)
    GSTEP(3, x0, x2, axB, axA, 1, 0)
  }
#undef GSTEP
#undef LOADX

  // ---- embedded kM: F-blocks (tf==1) run the MT/MF/c0 jobs on otherwise-idle CUs ----
  if (tf == 1) {
    int jid = bt * 2 + dir;  // 0..127
    for (int job = jid; job < 576; job += 128) {
      __syncthreads();
      int o = job & 63, by = job >> 6;
      if (by < 8) {
        int t0 = by * 32;
        const float* Wo = W1 + (size_t)o * 32768 + 16384;
        for (int idx = tid; idx < 16384; idx += 256) W1s[idx >> 7][idx & 127] = Wo[idx];
        for (int idx = tid; idx < 4096; idx += 256)
          ls[idx >> 5][idx & 31] = lTw[(idx >> 5) * 256 + t0 + (idx & 31)];
        __syncthreads();
        int c = tid & 127, th = tid >> 7;
        float acc[16];
#pragma unroll
        for (int q = 0; q < 16; ++q) acc[q] = 0.f;
        for (int t2 = 0; t2 < 128; ++t2) {
          float wv = W1s[c][t2];
#pragma unroll
          for (int q = 0; q < 16; ++q) acc[q] += wv * ls[t2][th + 2 * q];
        }
        float* Mo = MT + (size_t)o * 32768;
#pragma unroll
        for (int q = 0; q < 16; ++q) Mo[(t0 + th + 2 * q) * 128 + c] = acc[q];
      } else {
        const float* Wo = W1 + (size_t)o * 32768;
        for (int idx = tid; idx < 16384; idx += 256) W1s[idx >> 7][idx & 127] = Wo[idx];
        for (int idx = tid; idx < 640; idx += 256) ls[idx / 5][idx % 5] = lFw[idx];
        __syncthreads();
        int c = tid & 127, fh = tid >> 7;
        float acc[3] = {0.f, 0.f, 0.f};
        for (int t2 = 0; t2 < 128; ++t2) {
          float wv = W1s[c][t2];
#pragma unroll
          for (int q = 0; q < 3; ++q) {
            int f = fh + 2 * q;
            if (f < 5) acc[q] += wv * ls[t2][f];
          }
        }
#pragma unroll
        for (int q = 0; q < 3; ++q) {
          int f = fh + 2 * q;
          if (f < 5) MF[(size_t)o * 640 + f * 128 + c] = acc[q];
        }
        float s = 0.f;
        for (int idx = tid; idx < 16384; idx += 256) {
          int t2 = idx & 127;
          s += Wo[idx] * lFb[t2] + Wo[16384 + idx] * lTb[t2];
        }
        rs[tid] = s;
        __syncthreads();
        for (int off = 128; off; off >>= 1) {
          if (tid < off) rs[tid] += rs[tid + off];
          __syncthreads();
        }
        if (tid == 0) c0v[o] = l1b[o] + rs[0];
      }
    }
  }
}

// ============ BN stats (T and F in one grid) ============
__global__ __launch_bounds__(256) void kbn_all(
    const u16* __restrict__ gTp, const u16* __restrict__ gFp,
    const float* __restrict__ gamT, const float* __restrict__ betT,
    const float* __restrict__ gamF, const float* __restrict__ betF,
    float* __restrict__ sdT, float* __restrict__ sdF) {
  int bid = blockIdx.x, tid = threadIdx.x;
  const u16* g;
  const float *gam, *bet;
  float* sd;
  int S, t;
  if (bid < 256) {
    g = gTp; S = 256; t = bid; gam = gamT; bet = betT; sd = sdT;
  } else {
    g = gFp; S = 5; t = bid - 256; gam = gamF; bet = betF; sd = sdF;
  }
  float s = 0.f, s2 = 0.f;
  for (int unit = tid; unit < 32768; unit += 256) {
    int b = unit >> 5, c4 = (unit & 31) * 4;
    ushort4 u = *(const ushort4*)(g + ((size_t)b * S + t) * 128 + c4);
    float v0 = __uint_as_float((unsigned)u.x << 16);
    float v1 = __uint_as_float((unsigned)u.y << 16);
    float v2 = __uint_as_float((unsigned)u.z << 16);
    float v3 = __uint_as_float((unsigned)u.w << 16);
    s += v0 + v1 + v2 + v3;
    s2 += v0 * v0 + v1 * v1 + v2 * v2 + v3 * v3;
  }
  __shared__ float rs[256], rq[256];
  rs[tid] = s;
  rq[tid] = s2;
  __syncthreads();
  for (int off = 128; off; off >>= 1) {
    if (tid < off) {
      rs[tid] += rs[tid + off];
      rq[tid] += rq[tid + off];
    }
    __syncthreads();
  }
  if (tid == 0) {
    float inv_n = 1.f / (float)(B_ * C_);
    float m = rs[0] * inv_n;
    float var = rq[0] * inv_n - m * m;
    float inv = 1.f / sqrtf(var + 1e-5f);
    float sc = gam[t] * inv;
    sd[2 * t] = sc;
    sd[2 * t + 1] = bet[t] - m * sc;
  }
}

// ============ kchunk (32-batch/nt=16/17-slot form) ============
__global__ __launch_bounds__(256) void kchunk_all(
    const u16* __restrict__ gTp, const u16* __restrict__ gFp,
    const float* __restrict__ sdT, const float* __restrict__ sdF,
    const float* __restrict__ MT, const float* __restrict__ MF,
    float* __restrict__ part) {
  __shared__ float gs[32][132];
  __shared__ float Ms[64][132];
  int tid = threadIdx.x;
  int b0 = blockIdx.x * 32;
  int by = blockIdx.y;
  const u16* g;
  const float *sd, *M;
  int S, nt, t0, slot;
  if (by < 16) {
    g = gTp; sd = sdT; M = MT; S = 256; nt = 16; t0 = by * 16; slot = by;
  } else {
    g = gFp; sd = sdF; M = MF; S = 5; nt = 5; t0 = 0; slot = 16;
  }
  int ot = tid & 31, bt = tid >> 5;
  float acc[4][2];
#pragma unroll
  for (int i = 0; i < 4; ++i) {
    acc[i][0] = 0.f;
    acc[i][1] = 0.f;
  }
  for (int t = t0; t < t0 + nt; ++t) {
    __syncthreads();
    float sc = sd[2 * t], dd = sd[2 * t + 1];
    for (int idx = tid; idx < 1024; idx += 256) {
      int bb = idx >> 5, c4 = (idx & 31) * 4;
      ushort4 u = *(const ushort4*)(g + ((size_t)(b0 + bb) * S + t) * 128 + c4);
      gs[bb][c4 + 0] = __uint_as_float((unsigned)u.x << 16) * sc + dd;
      gs[bb][c4 + 1] = __uint_as_float((unsigned)u.y << 16) * sc + dd;
      gs[bb][c4 + 2] = __uint_as_float((unsigned)u.z << 16) * sc + dd;
      gs[bb][c4 + 3] = __uint_as_float((unsigned)u.w << 16) * sc + dd;
    }
    for (int idx = tid; idx < 2048; idx += 256) {
      int o = idx >> 5, c4 = (idx & 31) * 4;
      *(float4*)&Ms[o][c4] = *(const float4*)(M + ((size_t)o * S + t) * 128 + c4);
    }
    __syncthreads();
    for (int c = 0; c < 128; c += 4) {
      f32x4 m0 = *(const f32x4*)&Ms[ot][c];
      f32x4 m1 = *(const f32x4*)&Ms[ot + 32][c];
#pragma unroll
      for (int i = 0; i < 4; ++i) {
        f32x4 gv = *(const f32x4*)&gs[bt * 4 + i][c];
        acc[i][0] += gv[0] * m0[0] + gv[1] * m0[1] + gv[2] * m0[2] + gv[3] * m0[3];
        acc[i][1] += gv[0] * m1[0] + gv[1] * m1[1] + gv[2] * m1[2] + gv[3] * m1[3];
      }
    }
  }
#pragma unroll
  for (int i = 0; i < 4; ++i) {
    part[((size_t)slot * 1024 + b0 + bt * 4 + i) * 64 + ot] = acc[i][0];
    part[((size_t)slot * 1024 + b0 + bt * 4 + i) * 64 + ot + 32] = acc[i][1];
  }
}

// ============ finalize ============
__global__ __launch_bounds__(64) void kfin(const float* __restrict__ part,
                                           const float* __restrict__ c0,
                                           const float* __restrict__ l2w,
                                           const float* __restrict__ l2b,
                                           float* __restrict__ outp) {
  int b = blockIdx.x, o = threadIdx.x;
  float y = c0[o];
  for (int s = 0; s < 17; ++s) y += part[((size_t)s * 1024 + b) * 64 + o];
  y = leaky(y);
  __shared__ float a[64];
  a[o] = y;
  __syncthreads();
  if (o < 3) {
    float r = l2b[o];
    for (int j = 0; j < 64; ++j) r += l2w[o * 64 + j] * a[j];
    outp[b * 3 + o] = r;
  }
}

extern "C" void kernel_launch(void* const* d_in, const int* in_sizes, int n_in,
                              void* d_out, int out_size, void* d_ws, size_t ws_size,
                              hipStream_t stream) {
  const float* x_T = (const float*)d_in[0];
  const float* x_F = (const float*)d_in[1];
  const float* A = (const float*)d_in[2];
  const float* gcnw_F = (const float*)d_in[3];
  const float* gFwih_f = (const float*)d_in[4];
  const float* gFwhh_f = (const float*)d_in[5];
  const float* gFbih_f = (const float*)d_in[6];
  const float* gFbhh_f = (const float*)d_in[7];
  const float* gFwih_b = (const float*)d_in[8];
  const float* gFwhh_b = (const float*)d_in[9];
  const float* gFbih_b = (const float*)d_in[10];
  const float* gFbhh_b = (const float*)d_in[11];
  const float* bnFg = (const float*)d_in[12];
  const float* bnFb = (const float*)d_in[13];
  const float* gcnw_T = (const float*)d_in[14];
  const float* gTwih_f = (const float*)d_in[15];
  const float* gTwhh_f = (const float*)d_in[16];
  const float* gTbih_f = (const float*)d_in[17];
  const float* gTbhh_f = (const float*)d_in[18];
  const float* gTwih_b = (const float*)d_in[19];
  const float* gTwhh_b = (const float*)d_in[20];
  const float* gTbih_b = (const float*)d_in[21];
  const float* gTbhh_b = (const float*)d_in[22];
  const float* bnTg = (const float*)d_in[23];
  const float* bnTb = (const float*)d_in[24];
  const float* linF_w = (const float*)d_in[25];
  const float* linF_b = (const float*)d_in[26];
  const float* linT_w = (const float*)d_in[27];
  const float* linT_b = (const float*)d_in[28];
  const float* lin1_w = (const float*)d_in[29];
  const float* lin1_b = (const float*)d_in[30];
  const float* lin2_w = (const float*)d_in[31];
  const float* lin2_b = (const float*)d_in[32];

  char* w8 = (char*)d_ws;
  size_t off = 0;
  auto take = [&](size_t bytes) {
    void* p = w8 + off;
    off += (bytes + 255) & ~(size_t)255;
    return p;
  };
  float* XpT = (float*)take((size_t)1024 * 256 * 64 * 4);
  float* XpF = (float*)take((size_t)1024 * 5 * 64 * 4);
  u16* XfT = (u16*)take((size_t)64 * 256 * 2048 * 2);
  u16* XfF = (u16*)take((size_t)64 * 5 * 2048 * 2);
  u16* gT = (u16*)take((size_t)1024 * 256 * 128 * 2);
  u16* gF = (u16*)take((size_t)1024 * 5 * 128 * 2);
  float* sdT = (float*)take(512 * 4);
  float* sdF = (float*)take(16 * 4);
  float* MT = (float*)take((size_t)64 * 256 * 128 * 4);
  float* MF = (float*)take((size_t)64 * 5 * 128 * 4);
  float* c0 = (float*)take(64 * 4);
  float* part = (float*)take((size_t)17 * 1024 * 64 * 4);

  knorm_xc<<<1024, 256, 0, stream>>>(A, x_T, x_F, gcnw_T, gcnw_F, XpT, XpF);
  kxq_all<<<dim3(64, 66), 256, 0, stream>>>(XpT, XpF, XfT, XfF);
  kgru_all<<<dim3(64, 2, 2), 256, 0, stream>>>(
      XfT, XfF, gTwih_f, gTwhh_f, gTbih_f, gTbhh_f, gTwih_b, gTwhh_b, gTbih_b, gTbhh_b,
      gFwih_f, gFwhh_f, gFbih_f, gFbhh_f, gFwih_b, gFwhh_b, gFbih_b, gFbhh_b, gT, gF,
      lin1_w, linT_w, linF_w, linF_b, linT_b, lin1_b, MT, MF, c0);
  kbn_all<<<261, 256, 0, stream>>>(gT, gF, bnTg, bnTb, bnFg, bnFb, sdT, sdF);
  kchunk_all<<<dim3(32, 17), 256, 0, stream>>>(gT, gF, sdT, sdF, MT, MF, part);
  kfin<<<1024, 64, 0, stream>>>(part, c0, lin2_w, lin2_b, (float*)d_out);
}

// Round 22
// 419.998 us; speedup vs baseline: 1.2640x; 1.0572x over previous
//
#include <hip/hip_runtime.h>

#define B_ 1024
#define N_ 64
#define T_ 256
#define FB_ 5
#define T2_ 128
#define C_ 128  // 2N

typedef unsigned short u16;
typedef __attribute__((ext_vector_type(8))) short bf16x8;
typedef __attribute__((ext_vector_type(4))) float f32x4;

__device__ __forceinline__ float leaky(float x) { return x >= 0.f ? x : 0.01f * x; }
__device__ __forceinline__ float rcpf(float x) { return __builtin_amdgcn_rcpf(x); }
__device__ __forceinline__ float sigm2(float x) { return rcpf(1.f + __expf(-x)); }
__device__ __forceinline__ float tanh2(float x) { return 1.f - 2.f * rcpf(1.f + __expf(2.f * x)); }
__device__ __forceinline__ unsigned bf16_rne(float f) {
  unsigned u = __float_as_uint(f);
  return (u + 0x7FFFu + ((u >> 16) & 1u)) >> 16;
}
// barrier that does NOT drain vmcnt (keeps global prefetch in flight)
__device__ __forceinline__ void block_sync_lds() {
  __builtin_amdgcn_sched_barrier(0);
  asm volatile("s_waitcnt lgkmcnt(0)" ::: "memory");
  __builtin_amdgcn_s_barrier();
  __builtin_amdgcn_sched_barrier(0);
}

#define MFMA_(A, B, C) __builtin_amdgcn_mfma_f32_16x16x32_bf16(A, B, C, 0, 0, 0)

// ============ fused norm_adj + Xc(T) + Xc(F): HsT in LDS; 2 LDS instr / 16 FMA ============
__device__ __forceinline__ void xc_tile(const float (*HsT)[68], float (*xs)[68],
                                        const float* __restrict__ Xb, int S, int t0, float w,
                                        float* __restrict__ Ob, int tid) {
  __syncthreads();
  for (int idx = tid; idx < 4096; idx += 256) {
    int j = idx >> 6, tt = idx & 63;
    xs[j][tt] = (t0 + tt < S) ? Xb[j * S + t0 + tt] : 0.f;
  }
  __syncthreads();
  int i0 = (tid & 15) * 4, tl = (tid >> 4) * 4;
  f32x4 a0 = {0, 0, 0, 0}, a1 = {0, 0, 0, 0}, a2 = {0, 0, 0, 0}, a3 = {0, 0, 0, 0};
#pragma unroll 4
  for (int j = 0; j < 64; ++j) {
    f32x4 hv = *(const f32x4*)&HsT[j][i0];
    f32x4 xv = *(const f32x4*)&xs[j][tl];
    a0 += hv * xv[0];
    a1 += hv * xv[1];
    a2 += hv * xv[2];
    a3 += hv * xv[3];
  }
#define STORE_T(K, AV)                                  \
  {                                                     \
    int t = t0 + tl + K;                                \
    if (t < S) {                                        \
      f32x4 r;                                          \
      _Pragma("unroll") for (int e = 0; e < 4; ++e)     \
          r[e] = leaky(w * AV[e]);                      \
      *(f32x4*)&Ob[(size_t)t * 64 + i0] = r;            \
    }                                                   \
  }
  STORE_T(0, a0)
  STORE_T(1, a1)
  STORE_T(2, a2)
  STORE_T(3, a3)
#undef STORE_T
}

__global__ __launch_bounds__(256) void knorm_xc(
    const float* __restrict__ A, const float* __restrict__ xT, const float* __restrict__ xF,
    const float* __restrict__ wT, const float* __restrict__ wF,
    float* __restrict__ XpT, float* __restrict__ XpF) {
  __shared__ float HsT[64][68];  // HsT[j][i]
  __shared__ float dinv[64];
  __shared__ float xs[64][68];
  int b = blockIdx.x, tid = threadIdx.x;
  const float* Ab = A + (size_t)b * 4096;
  for (int idx = tid; idx < 4096; idx += 256) {
    int i = idx >> 6, j = idx & 63;
    HsT[j][i] = (i == j) ? 1.f : Ab[idx];
  }
  __syncthreads();
  if (tid < 64) {
    float s = 0.f;
    for (int j = 0; j < 64; ++j) s += HsT[j][tid];
    dinv[tid] = 1.f / sqrtf(s);
  }
  __syncthreads();
  for (int idx = tid; idx < 4096; idx += 256) {
    int j = idx >> 6, i = idx & 63;
    HsT[j][i] *= dinv[i] * dinv[j];
  }
  {
    const float* Xb = xT + (size_t)b * 64 * 256;
    float w = wT[0];
    float* Ob = XpT + (size_t)b * 256 * 64;
    for (int t0 = 0; t0 < 256; t0 += 64) xc_tile(HsT, xs, Xb, 256, t0, w, Ob, tid);
  }
  {
    const float* Xb = xF + (size_t)b * 64 * 5;
    float w = wF[0];
    float* Ob = XpF + (size_t)b * 5 * 64;
    xc_tile(HsT, xs, Xb, 5, 0, w, Ob, tid);
  }
}

// ============ repack Xp -> bf16 (hi only) lane-major MFMA B-fragments ============
// Xf unit per (bt,t): 1024 u16 = [kh(2)][lane(64)][e(8)]
__global__ __launch_bounds__(256) void kxq_all(const float* __restrict__ XpT,
                                               const float* __restrict__ XpF,
                                               u16* __restrict__ XfT, u16* __restrict__ XfF) {
  __shared__ float xs[4][16][68];
  int bt = blockIdx.x, by = blockIdx.y, tid = threadIdx.x;
  const float* Xp;
  u16* Xf;
  int S, t0;
  if (by < 64) {
    Xp = XpT; Xf = XfT; S = 256; t0 = by * 4;
  } else {
    Xp = XpF; Xf = XfF; S = 5; t0 = (by - 64) * 4;
  }
  for (int idx = tid; idx < 1024; idx += 256) {
    int b_l = idx >> 6, rest = idx & 63, t_l = rest >> 4, c = rest & 15;
    float4 v = {0.f, 0.f, 0.f, 0.f};
    if (t0 + t_l < S)
      v = *(const float4*)(Xp + ((size_t)(bt * 16 + b_l) * S + t0 + t_l) * 64 + c * 4);
    *(float4*)&xs[t_l][b_l][c * 4] = v;
  }
  __syncthreads();
  int t_l = tid >> 6, lane = tid & 63, blo = lane & 15, grp = lane >> 4;
  int t = t0 + t_l;
  if (t >= S) return;
#pragma unroll
  for (int kh = 0; kh < 2; ++kh) {
    const f32x4* src = (const f32x4*)&xs[t_l][blo][kh * 32 + grp * 8];
    f32x4 a0 = src[0], a1 = src[1];
    bf16x8 hi;
#pragma unroll
    for (int e = 0; e < 4; ++e) {
      hi[e] = (short)bf16_rne(a0[e]);
      hi[e + 4] = (short)bf16_rne(a1[e]);
    }
    u16* dst = Xf + (size_t)(bt * S + t) * 1024 + (size_t)kh * 512 + lane * 8;
    *(bf16x8*)dst = hi;
  }
}

// ============ MFMA bidirectional GRU (T/F), full bf16: 12 MFMAs/step ============
// ax: Whi*xh -> 6 MFMAs; ah: Whh_hi*h -> 6 MFMAs (2-deep chain per gate).
// + embedded kM on the F-blocks' idle CUs.
__device__ __forceinline__ void axcomp(f32x4 (&AX)[3], const bf16x8 (&XB)[2],
                                       const bf16x8 (&Whi)[3][2], const f32x4 (&bI)[3]) {
  AX[0] = bI[0];
  AX[1] = bI[1];
  AX[2] = bI[2];
#pragma unroll
  for (int kh = 0; kh < 2; ++kh) {
    bf16x8 xh = XB[kh];
#pragma unroll
    for (int gi = 0; gi < 3; ++gi) {
      AX[gi] = MFMA_(Whi[gi][kh], xh, AX[gi]);
    }
  }
}

__global__ __launch_bounds__(256, 1) void kgru_all(
    const u16* __restrict__ XfT, const u16* __restrict__ XfF,
    const float* __restrict__ Twih_f, const float* __restrict__ Twhh_f,
    const float* __restrict__ Tbih_f, const float* __restrict__ Tbhh_f,
    const float* __restrict__ Twih_b, const float* __restrict__ Twhh_b,
    const float* __restrict__ Tbih_b, const float* __restrict__ Tbhh_b,
    const float* __restrict__ Fwih_f, const float* __restrict__ Fwhh_f,
    const float* __restrict__ Fbih_f, const float* __restrict__ Fbhh_f,
    const float* __restrict__ Fwih_b, const float* __restrict__ Fwhh_b,
    const float* __restrict__ Fbih_b, const float* __restrict__ Fbhh_b,
    u16* __restrict__ gT, u16* __restrict__ gF,
    const float* __restrict__ W1, const float* __restrict__ lTw, const float* __restrict__ lFw,
    const float* __restrict__ lFb, const float* __restrict__ lTb, const float* __restrict__ l1b,
    float* __restrict__ MT, float* __restrict__ MF, float* __restrict__ c0v) {
  __shared__ u16 Hhi[2][16][72];
  __shared__ float W1s[128][129];
  __shared__ float ls[128][32];
  __shared__ float rs[256];
  int tid = threadIdx.x;
  int w = tid >> 6, lane = tid & 63, blo = lane & 15, grp = lane >> 4;
  int bt = blockIdx.x, dir = blockIdx.y, tf = blockIdx.z;
  int S = tf ? 5 : 256;
  const u16* Xf = tf ? XfF : XfT;
  u16* g = tf ? gF : gT;
  const float* wih = tf ? (dir ? Fwih_b : Fwih_f) : (dir ? Twih_b : Twih_f);
  const float* whh = tf ? (dir ? Fwhh_b : Fwhh_f) : (dir ? Twhh_b : Twhh_f);
  const float* bih = tf ? (dir ? Fbih_b : Fbih_f) : (dir ? Tbih_b : Tbih_f);
  const float* bhh = tf ? (dir ? Fbhh_b : Fbhh_f) : (dir ? Tbhh_b : Tbhh_f);

  for (int idx = tid; idx < 2 * 16 * 72; idx += 256) {
    ((u16*)Hhi)[idx] = 0;
  }

  // bf16-rounded weight fragments (no lo compensation)
  bf16x8 Wih_hi[3][2], Whh_hi[3][2];
#pragma unroll
  for (int gi = 0; gi < 3; ++gi) {
    int k = (gi * 4 + w) * 16 + blo;
#pragma unroll
    for (int kh = 0; kh < 2; ++kh) {
      int j0 = kh * 32 + grp * 8;
#pragma unroll
      for (int m = 0; m < 2; ++m) {
        const float* src = (m ? whh : wih) + (size_t)k * 64 + j0;
        f32x4 a0 = *(const f32x4*)src;
        f32x4 a1 = *(const f32x4*)(src + 4);
        bf16x8 hi;
#pragma unroll
        for (int e = 0; e < 4; ++e) {
          hi[e] = (short)bf16_rne(a0[e]);
          hi[e + 4] = (short)bf16_rne(a1[e]);
        }
        if (m) Whh_hi[gi][kh] = hi;
        else Wih_hi[gi][kh] = hi;
      }
    }
  }
  f32x4 bI[3], bH[3];
#pragma unroll
  for (int gi = 0; gi < 3; ++gi) {
    int k0 = (gi * 4 + w) * 16 + 4 * grp;
    bI[gi] = *(const f32x4*)(bih + k0);
    bH[gi] = *(const f32x4*)(bhh + k0);
  }

  float ho[4] = {0.f, 0.f, 0.f, 0.f};
  int j0q = 16 * w + 4 * grp;
  const u16* xbase = Xf + (size_t)bt * S * 1024 + lane * 8;
  long long sstep = dir ? -2048LL : 2048LL;  // bytes per step (1024 u16)
  long long gstep = dir ? -256LL : 256LL;

  bf16x8 x0[2], x1[2], x2[2], x3[2];
#define LOADX(DST, TR)                            \
  {                                               \
    const u16* xp = xbase + (size_t)(TR) * 1024;  \
    DST[0] = *(const bf16x8*)(xp);                \
    DST[1] = *(const bf16x8*)(xp + 512);          \
  }
  LOADX(x0, dir ? (S - 1) : 0)
  if (S > 1) LOADX(x1, dir ? (S - 2) : 1)
  if (S > 2) LOADX(x2, dir ? (S - 3) : 2)
  const u16* xw = xbase + (size_t)(dir ? (S >= 4 ? S - 4 : 0) : 3) * 1024;
  u16* gp = g + ((size_t)(bt * 16 + blo) * S + (dir ? S - 1 : 0)) * 128 + dir * 64 + j0q;

  f32x4 axA[3], axB[3];
  axcomp(axA, x0, Wih_hi, bI);
  block_sync_lds();

#define GSTEP(KK, XAX, XLD, AXC, AXN, PR, PW)                                        \
  {                                                                                  \
    int t = tbase + KK;                                                              \
    if (t < S) {                                                                     \
      bf16x8 h0h = *(const bf16x8*)&Hhi[PR][blo][grp * 8];                           \
      bf16x8 h1h = *(const bf16x8*)&Hhi[PR][blo][32 + grp * 8];                      \
      if (t + 3 < S) {                                                               \
        XLD[0] = *(const bf16x8*)(xw);                                               \
        XLD[1] = *(const bf16x8*)(xw + 512);                                         \
        xw = (const u16*)((const char*)xw + sstep);                                  \
      }                                                                              \
      if (t + 1 < S) axcomp(AXN, XAX, Wih_hi, bI);                                   \
      f32x4 ahr = bH[0], ahz = bH[1], ahn = bH[2];                                   \
      ahr = MFMA_(Whh_hi[0][0], h0h, ahr);                                           \
      ahz = MFMA_(Whh_hi[1][0], h0h, ahz);                                           \
      ahn = MFMA_(Whh_hi[2][0], h0h, ahn);                                           \
      ahr = MFMA_(Whh_hi[0][1], h1h, ahr);                                           \
      ahz = MFMA_(Whh_hi[1][1], h1h, ahz);                                           \
      ahn = MFMA_(Whh_hi[2][1], h1h, ahn);                                           \
      u16 hi_u[4];                                                                   \
      _Pragma("unroll") for (int u = 0; u < 4; ++u) {                                \
        float r = sigm2(AXC[0][u] + ahr[u]);                                         \
        float z = sigm2(AXC[1][u] + ahz[u]);                                         \
        float n = tanh2(AXC[2][u] + r * ahn[u]);                                     \
        float h = n + z * (ho[u] - n);                                               \
        ho[u] = h;                                                                   \
        hi_u[u] = (u16)((__float_as_uint(h) + 0x8000u) >> 16);                       \
      }                                                                              \
      ushort4 h4;                                                                    \
      h4.x = hi_u[0]; h4.y = hi_u[1]; h4.z = hi_u[2]; h4.w = hi_u[3];                \
      *(ushort4*)&Hhi[PW][blo][j0q] = h4;                                            \
      *(ushort4*)gp = h4;                                                            \
      gp = (u16*)((char*)gp + gstep);                                                \
      block_sync_lds();                                                              \
    }                                                                                \
  }

  for (int tbase = 0; tbase < S; tbase += 4) {
    GSTEP(0, x1, x3, axA, axB, 0, 1)
    GSTEP(1, x2, x0, axB, axA, 1, 0)
    GSTEP(2, x3, x1, axA, axB, 0, 1)
    GSTEP(3, x0, x2, axB, axA, 1, 0)
  }
#undef GSTEP
#undef LOADX

  // ---- embedded kM: F-blocks (tf==1) run the MT/MF/c0 jobs on otherwise-idle CUs ----
  if (tf == 1) {
    int jid = bt * 2 + dir;  // 0..127
    for (int job = jid; job < 576; job += 128) {
      __syncthreads();
      int o = job & 63, by = job >> 6;
      if (by < 8) {
        int t0 = by * 32;
        const float* Wo = W1 + (size_t)o * 32768 + 16384;
        for (int idx = tid; idx < 16384; idx += 256) W1s[idx >> 7][idx & 127] = Wo[idx];
        for (int idx = tid; idx < 4096; idx += 256)
          ls[idx >> 5][idx & 31] = lTw[(idx >> 5) * 256 + t0 + (idx & 31)];
        __syncthreads();
        int c = tid & 127, th = tid >> 7;
        float acc[16];
#pragma unroll
        for (int q = 0; q < 16; ++q) acc[q] = 0.f;
        for (int t2 = 0; t2 < 128; ++t2) {
          float wv = W1s[c][t2];
#pragma unroll
          for (int q = 0; q < 16; ++q) acc[q] += wv * ls[t2][th + 2 * q];
        }
        float* Mo = MT + (size_t)o * 32768;
#pragma unroll
        for (int q = 0; q < 16; ++q) Mo[(t0 + th + 2 * q) * 128 + c] = acc[q];
      } else {
        const float* Wo = W1 + (size_t)o * 32768;
        for (int idx = tid; idx < 16384; idx += 256) W1s[idx >> 7][idx & 127] = Wo[idx];
        for (int idx = tid; idx < 640; idx += 256) ls[idx / 5][idx % 5] = lFw[idx];
        __syncthreads();
        int c = tid & 127, fh = tid >> 7;
        float acc[3] = {0.f, 0.f, 0.f};
        for (int t2 = 0; t2 < 128; ++t2) {
          float wv = W1s[c][t2];
#pragma unroll
          for (int q = 0; q < 3; ++q) {
            int f = fh + 2 * q;
            if (f < 5) acc[q] += wv * ls[t2][f];
          }
        }
#pragma unroll
        for (int q = 0; q < 3; ++q) {
          int f = fh + 2 * q;
          if (f < 5) MF[(size_t)o * 640 + f * 128 + c] = acc[q];
        }
        float s = 0.f;
        for (int idx = tid; idx < 16384; idx += 256) {
          int t2 = idx & 127;
          s += Wo[idx] * lFb[t2] + Wo[16384 + idx] * lTb[t2];
        }
        rs[tid] = s;
        __syncthreads();
        for (int off = 128; off; off >>= 1) {
          if (tid < off) rs[tid] += rs[tid + off];
          __syncthreads();
        }
        if (tid == 0) c0v[o] = l1b[o] + rs[0];
      }
    }
  }
}

// ============ BN stats (T and F in one grid) ============
__global__ __launch_bounds__(256) void kbn_all(
    const u16* __restrict__ gTp, const u16* __restrict__ gFp,
    const float* __restrict__ gamT, const float* __restrict__ betT,
    const float* __restrict__ gamF, const float* __restrict__ betF,
    float* __restrict__ sdT, float* __restrict__ sdF) {
  int bid = blockIdx.x, tid = threadIdx.x;
  const u16* g;
  const float *gam, *bet;
  float* sd;
  int S, t;
  if (bid < 256) {
    g = gTp; S = 256; t = bid; gam = gamT; bet = betT; sd = sdT;
  } else {
    g = gFp; S = 5; t = bid - 256; gam = gamF; bet = betF; sd = sdF;
  }
  float s = 0.f, s2 = 0.f;
  for (int unit = tid; unit < 32768; unit += 256) {
    int b = unit >> 5, c4 = (unit & 31) * 4;
    ushort4 u = *(const ushort4*)(g + ((size_t)b * S + t) * 128 + c4);
    float v0 = __uint_as_float((unsigned)u.x << 16);
    float v1 = __uint_as_float((unsigned)u.y << 16);
    float v2 = __uint_as_float((unsigned)u.z << 16);
    float v3 = __uint_as_float((unsigned)u.w << 16);
    s += v0 + v1 + v2 + v3;
    s2 += v0 * v0 + v1 * v1 + v2 * v2 + v3 * v3;
  }
  __shared__ float rs[256], rq[256];
  rs[tid] = s;
  rq[tid] = s2;
  __syncthreads();
  for (int off = 128; off; off >>= 1) {
    if (tid < off) {
      rs[tid] += rs[tid + off];
      rq[tid] += rq[tid + off];
    }
    __syncthreads();
  }
  if (tid == 0) {
    float inv_n = 1.f / (float)(B_ * C_);
    float m = rs[0] * inv_n;
    float var = rq[0] * inv_n - m * m;
    float inv = 1.f / sqrtf(var + 1e-5f);
    float sc = gam[t] * inv;
    sd[2 * t] = sc;
    sd[2 * t + 1] = bet[t] - m * sc;
  }
}

// ============ kchunk (32-batch/nt=16/17-slot form) ============
__global__ __launch_bounds__(256) void kchunk_all(
    const u16* __restrict__ gTp, const u16* __restrict__ gFp,
    const float* __restrict__ sdT, const float* __restrict__ sdF,
    const float* __restrict__ MT, const float* __restrict__ MF,
    float* __restrict__ part) {
  __shared__ float gs[32][132];
  __shared__ float Ms[64][132];
  int tid = threadIdx.x;
  int b0 = blockIdx.x * 32;
  int by = blockIdx.y;
  const u16* g;
  const float *sd, *M;
  int S, nt, t0, slot;
  if (by < 16) {
    g = gTp; sd = sdT; M = MT; S = 256; nt = 16; t0 = by * 16; slot = by;
  } else {
    g = gFp; sd = sdF; M = MF; S = 5; nt = 5; t0 = 0; slot = 16;
  }
  int ot = tid & 31, bt = tid >> 5;
  float acc[4][2];
#pragma unroll
  for (int i = 0; i < 4; ++i) {
    acc[i][0] = 0.f;
    acc[i][1] = 0.f;
  }
  for (int t = t0; t < t0 + nt; ++t) {
    __syncthreads();
    float sc = sd[2 * t], dd = sd[2 * t + 1];
    for (int idx = tid; idx < 1024; idx += 256) {
      int bb = idx >> 5, c4 = (idx & 31) * 4;
      ushort4 u = *(const ushort4*)(g + ((size_t)(b0 + bb) * S + t) * 128 + c4);
      gs[bb][c4 + 0] = __uint_as_float((unsigned)u.x << 16) * sc + dd;
      gs[bb][c4 + 1] = __uint_as_float((unsigned)u.y << 16) * sc + dd;
      gs[bb][c4 + 2] = __uint_as_float((unsigned)u.z << 16) * sc + dd;
      gs[bb][c4 + 3] = __uint_as_float((unsigned)u.w << 16) * sc + dd;
    }
    for (int idx = tid; idx < 2048; idx += 256) {
      int o = idx >> 5, c4 = (idx & 31) * 4;
      *(float4*)&Ms[o][c4] = *(const float4*)(M + ((size_t)o * S + t) * 128 + c4);
    }
    __syncthreads();
    for (int c = 0; c < 128; c += 4) {
      f32x4 m0 = *(const f32x4*)&Ms[ot][c];
      f32x4 m1 = *(const f32x4*)&Ms[ot + 32][c];
#pragma unroll
      for (int i = 0; i < 4; ++i) {
        f32x4 gv = *(const f32x4*)&gs[bt * 4 + i][c];
        acc[i][0] += gv[0] * m0[0] + gv[1] * m0[1] + gv[2] * m0[2] + gv[3] * m0[3];
        acc[i][1] += gv[0] * m1[0] + gv[1] * m1[1] + gv[2] * m1[2] + gv[3] * m1[3];
      }
    }
  }
#pragma unroll
  for (int i = 0; i < 4; ++i) {
    part[((size_t)slot * 1024 + b0 + bt * 4 + i) * 64 + ot] = acc[i][0];
    part[((size_t)slot * 1024 + b0 + bt * 4 + i) * 64 + ot + 32] = acc[i][1];
  }
}

// ============ finalize ============
__global__ __launch_bounds__(64) void kfin(const float* __restrict__ part,
                                           const float* __restrict__ c0,
                                           const float* __restrict__ l2w,
                                           const float* __restrict__ l2b,
                                           float* __restrict__ outp) {
  int b = blockIdx.x, o = threadIdx.x;
  float y = c0[o];
  for (int s = 0; s < 17; ++s) y += part[((size_t)s * 1024 + b) * 64 + o];
  y = leaky(y);
  __shared__ float a[64];
  a[o] = y;
  __syncthreads();
  if (o < 3) {
    float r = l2b[o];
    for (int j = 0; j < 64; ++j) r += l2w[o * 64 + j] * a[j];
    outp[b * 3 + o] = r;
  }
}

extern "C" void kernel_launch(void* const* d_in, const int* in_sizes, int n_in,
                              void* d_out, int out_size, void* d_ws, size_t ws_size,
                              hipStream_t stream) {
  const float* x_T = (const float*)d_in[0];
  const float* x_F = (const float*)d_in[1];
  const float* A = (const float*)d_in[2];
  const float* gcnw_F = (const float*)d_in[3];
  const float* gFwih_f = (const float*)d_in[4];
  const float* gFwhh_f = (const float*)d_in[5];
  const float* gFbih_f = (const float*)d_in[6];
  const float* gFbhh_f = (const float*)d_in[7];
  const float* gFwih_b = (const float*)d_in[8];
  const float* gFwhh_b = (const float*)d_in[9];
  const float* gFbih_b = (const float*)d_in[10];
  const float* gFbhh_b = (const float*)d_in[11];
  const float* bnFg = (const float*)d_in[12];
  const float* bnFb = (const float*)d_in[13];
  const float* gcnw_T = (const float*)d_in[14];
  const float* gTwih_f = (const float*)d_in[15];
  const float* gTwhh_f = (const float*)d_in[16];
  const float* gTbih_f = (const float*)d_in[17];
  const float* gTbhh_f = (const float*)d_in[18];
  const float* gTwih_b = (const float*)d_in[19];
  const float* gTwhh_b = (const float*)d_in[20];
  const float* gTbih_b = (const float*)d_in[21];
  const float* gTbhh_b = (const float*)d_in[22];
  const float* bnTg = (const float*)d_in[23];
  const float* bnTb = (const float*)d_in[24];
  const float* linF_w = (const float*)d_in[25];
  const float* linF_b = (const float*)d_in[26];
  const float* linT_w = (const float*)d_in[27];
  const float* linT_b = (const float*)d_in[28];
  const float* lin1_w = (const float*)d_in[29];
  const float* lin1_b = (const float*)d_in[30];
  const float* lin2_w = (const float*)d_in[31];
  const float* lin2_b = (const float*)d_in[32];

  char* w8 = (char*)d_ws;
  size_t off = 0;
  auto take = [&](size_t bytes) {
    void* p = w8 + off;
    off += (bytes + 255) & ~(size_t)255;
    return p;
  };
  float* XpT = (float*)take((size_t)1024 * 256 * 64 * 4);
  float* XpF = (float*)take((size_t)1024 * 5 * 64 * 4);
  u16* XfT = (u16*)take((size_t)64 * 256 * 1024 * 2);
  u16* XfF = (u16*)take((size_t)64 * 5 * 1024 * 2);
  u16* gT = (u16*)take((size_t)1024 * 256 * 128 * 2);
  u16* gF = (u16*)take((size_t)1024 * 5 * 128 * 2);
  float* sdT = (float*)take(512 * 4);
  float* sdF = (float*)take(16 * 4);
  float* MT = (float*)take((size_t)64 * 256 * 128 * 4);
  float* MF = (float*)take((size_t)64 * 5 * 128 * 4);
  float* c0 = (float*)take(64 * 4);
  float* part = (float*)take((size_t)17 * 1024 * 64 * 4);

  knorm_xc<<<1024, 256, 0, stream>>>(A, x_T, x_F, gcnw_T, gcnw_F, XpT, XpF);
  kxq_all<<<dim3(64, 66), 256, 0, stream>>>(XpT, XpF, XfT, XfF);
  kgru_all<<<dim3(64, 2, 2), 256, 0, stream>>>(
      XfT, XfF, gTwih_f, gTwhh_f, gTbih_f, gTbhh_f, gTwih_b, gTwhh_b, gTbih_b, gTbhh_b,
      gFwih_f, gFwhh_f, gFbih_f, gFbhh_f, gFwih_b, gFwhh_b, gFbih_b, gFbhh_b, gT, gF,
      lin1_w, linT_w, linF_w, linF_b, linT_b, lin1_b, MT, MF, c0);
  kbn_all<<<261, 256, 0, stream>>>(gT, gF, bnTg, bnTb, bnFg, bnFb, sdT, sdF);
  kchunk_all<<<dim3(32, 17), 256, 0, stream>>>(gT, gF, sdT, sdF, MT, MF, part);
  kfin<<<1024, 64, 0, stream>>>(part, c0, lin2_w, lin2_b, (float*)d_out);
}